// Round 1
// baseline (563.356 us; speedup 1.0000x reference)
//
#include <hip/hip_runtime.h>
#include <math.h>

#define NNODES 50000
#define NEDGES 800000
#define SCAN_B 256

// ---------------- CSR build ----------------

__global__ void count_deg_kernel(const int* __restrict__ ei, int* __restrict__ deg, int E, int n){
  int i = blockIdx.x*blockDim.x + threadIdx.x;
  if (i >= E + n) return;
  int d = (i < E) ? ei[E + i] : (i - E);   // row 1 of edge_index = dst; then self-loops
  atomicAdd(&deg[d], 1);
}

__global__ void scan1_kernel(const int* __restrict__ deg, int* __restrict__ rowptr,
                             int* __restrict__ bsums, int n){
  __shared__ int s[SCAN_B];
  int tid = threadIdx.x;
  int i = blockIdx.x*SCAN_B + tid;
  int v = (i < n) ? deg[i] : 0;
  s[tid] = v; __syncthreads();
  for (int off = 1; off < SCAN_B; off <<= 1){
    int t = (tid >= off) ? s[tid - off] : 0;
    __syncthreads();
    s[tid] += t;
    __syncthreads();
  }
  if (i < n) rowptr[i] = s[tid] - v;            // exclusive
  if (tid == SCAN_B-1) bsums[blockIdx.x] = s[tid];
}

__global__ void scan2_kernel(int* __restrict__ bsums, int nb){
  __shared__ int s[SCAN_B];
  int tid = threadIdx.x;
  int v = (tid < nb) ? bsums[tid] : 0;
  s[tid] = v; __syncthreads();
  for (int off = 1; off < SCAN_B; off <<= 1){
    int t = (tid >= off) ? s[tid - off] : 0;
    __syncthreads();
    s[tid] += t;
    __syncthreads();
  }
  if (tid < nb) bsums[tid] = s[tid] - v;        // exclusive
}

__global__ void scan3_kernel(int* __restrict__ rowptr, const int* __restrict__ bsums,
                             int* __restrict__ cursor, int n, int total){
  int i = blockIdx.x*SCAN_B + threadIdx.x;
  if (i < n){
    int r = rowptr[i] + bsums[blockIdx.x];
    rowptr[i] = r; cursor[i] = r;
  }
  if (i == 0) rowptr[n] = total;
}

__global__ void fill_csr_kernel(const int* __restrict__ ei, int* __restrict__ cursor,
                                int* __restrict__ csr_src, int E, int n){
  int i = blockIdx.x*blockDim.x + threadIdx.x;
  if (i >= E + n) return;
  int s, d;
  if (i < E){ s = ei[i]; d = ei[E+i]; } else { s = i - E; d = s; }
  int pos = atomicAdd(&cursor[d], 1);
  csr_src[pos] = s;
}

// ---------------- SIMT f32 GEMM (64x64 tile, BK=16, 256 thr, 4x4 microtile) ----------------

template<bool BIAS, bool RELU>
__global__ void gemm_kernel(const float* __restrict__ A, const float* __restrict__ B,
                            const float* __restrict__ bias, float* __restrict__ C,
                            int M, int K, int N){
  const int BM=64, BN=64, BK=16;
  __shared__ float As[BK][BM+1];   // +1 pad: avoids 16-way bank conflict on staging writes
  __shared__ float Bs[BK][BN];
  int tid = threadIdx.x;
  int tr = tid >> 4, tc = tid & 15;
  int row0 = blockIdx.x * BM, col0 = blockIdx.y * BN;
  float acc[4][4] = {};
  for (int k0 = 0; k0 < K; k0 += BK){
    #pragma unroll
    for (int l = 0; l < 4; l++){
      int idx = tid + l*256;
      int ml = idx >> 4, kk = idx & 15;     // consecutive tid -> consecutive k: coalesced
      int m = row0 + ml;
      As[kk][ml] = (m < M) ? A[(size_t)m*K + k0 + kk] : 0.f;
    }
    #pragma unroll
    for (int l = 0; l < 4; l++){
      int idx = tid + l*256;
      int kk = idx >> 6, nl = idx & 63;     // coalesced along N
      Bs[kk][nl] = B[(size_t)(k0+kk)*N + col0 + nl];
    }
    __syncthreads();
    #pragma unroll
    for (int kk = 0; kk < BK; kk++){
      float a[4], b[4];
      #pragma unroll
      for (int i = 0; i < 4; i++) a[i] = As[kk][tr*4+i];
      #pragma unroll
      for (int j = 0; j < 4; j++) b[j] = Bs[kk][tc*4+j];
      #pragma unroll
      for (int i = 0; i < 4; i++)
        #pragma unroll
        for (int j = 0; j < 4; j++)
          acc[i][j] += a[i]*b[j];
    }
    __syncthreads();
  }
  #pragma unroll
  for (int i = 0; i < 4; i++){
    int m = row0 + tr*4 + i;
    if (m >= M) continue;
    #pragma unroll
    for (int j = 0; j < 4; j++){
      int c = col0 + tc*4 + j;
      float v = acc[i][j];
      if (BIAS) v += bias[c];
      if (RELU) v = fmaxf(v, 0.f);
      C[(size_t)m*N + c] = v;
    }
  }
}

// ---------------- per-node attention coefficients: alpha = h . a ----------------

template<int C>
__global__ void alpha_kernel(const float* __restrict__ h, const float* __restrict__ av_s,
                             const float* __restrict__ av_d, float* __restrict__ os,
                             float* __restrict__ od, int n){
  int gid = blockIdx.x*blockDim.x + threadIdx.x;
  int wave = gid >> 6, lane = gid & 63;
  if (wave >= n) return;
  float ps = 0.f, pd = 0.f;
  #pragma unroll
  for (int v = 0; v < C/64; v++){
    float hv = h[(size_t)wave*C + v*64 + lane];
    ps += hv * av_s[v*64 + lane];
    pd += hv * av_d[v*64 + lane];
  }
  #pragma unroll
  for (int off = 32; off > 0; off >>= 1){
    ps += __shfl_down(ps, off);
    pd += __shfl_down(pd, off);
  }
  if (lane == 0){ os[wave] = ps; od[wave] = pd; }
}

// ---------------- one wave64 per dst node: online segment-softmax + aggregate ----------------

template<int C>
__global__ void gat_agg_kernel(const int* __restrict__ rowptr, const int* __restrict__ csr_src,
                               const float* __restrict__ h, const float* __restrict__ as,
                               const float* __restrict__ ad, const float* __restrict__ bias,
                               float* __restrict__ out, int n){
  int gid = blockIdx.x*blockDim.x + threadIdx.x;
  int dst = gid >> 6, lane = gid & 63;
  if (dst >= n) return;
  constexpr int V = C/64;
  float adval = ad[dst];
  int r0 = rowptr[dst], r1 = rowptr[dst+1];
  float m = -INFINITY, denom = 0.f;
  float acc[V];
  #pragma unroll
  for (int v = 0; v < V; v++) acc[v] = 0.f;
  for (int j = r0; j < r1; ++j){
    int s = csr_src[j];
    float e = as[s] + adval;              // same addr all lanes -> broadcast load
    e = (e > 0.f) ? e : 0.2f*e;           // leaky_relu 0.2
    float mn = fmaxf(m, e);
    float scale = __expf(m - mn);         // first iter: exp(-inf)=0
    float w = __expf(e - mn);
    denom = denom*scale + w;
    #pragma unroll
    for (int v = 0; v < V; v++)
      acc[v] = acc[v]*scale + w * h[(size_t)s*C + v*64 + lane];
    m = mn;
  }
  float inv = 1.f / denom;                // every node has a self-loop -> denom >= 1
  #pragma unroll
  for (int v = 0; v < V; v++){
    float o = acc[v]*inv + bias[v*64 + lane];
    out[(size_t)dst*C + v*64 + lane] = fmaxf(o, 0.f);   // relu fused (applied after both GATs)
  }
}

// ---------------- launch ----------------

extern "C" void kernel_launch(void* const* d_in, const int* in_sizes, int n_in,
                              void* d_out, int out_size, void* d_ws, size_t ws_size,
                              hipStream_t stream){
  const float* x   = (const float*)d_in[0];
  const int*   ei  = (const int*)d_in[1];
  // d_in[2] = batch, unused by the reference
  const float* W1  = (const float*)d_in[3];
  const float* a1s = (const float*)d_in[4];
  const float* a1d = (const float*)d_in[5];
  const float* b1  = (const float*)d_in[6];
  const float* W2  = (const float*)d_in[7];
  const float* a2s = (const float*)d_in[8];
  const float* a2d = (const float*)d_in[9];
  const float* b2  = (const float*)d_in[10];
  const float* Wm1 = (const float*)d_in[11];
  const float* bm1 = (const float*)d_in[12];
  const float* Wm2 = (const float*)d_in[13];
  const float* bm2 = (const float*)d_in[14];
  float* out = (float*)d_out;

  const int N = NNODES, E = NEDGES;
  const int TOT = E + N;

  char* w = (char*)d_ws;
  auto alloc = [&](size_t bytes)->void*{
    void* p = (void*)w;
    w += (bytes + 255) & ~(size_t)255;
    return p;
  };
  int*   deg     = (int*)alloc((size_t)N*4);
  int*   cursor  = (int*)alloc((size_t)N*4);
  int*   rowptr  = (int*)alloc((size_t)(N+1)*4);
  int*   bsums   = (int*)alloc(256*4);
  int*   csr_src = (int*)alloc((size_t)TOT*4);
  float* h1      = (float*)alloc((size_t)N*128*4);
  float* as1     = (float*)alloc((size_t)N*4);
  float* ad1     = (float*)alloc((size_t)N*4);
  float* out1    = (float*)alloc((size_t)N*128*4);
  float* h2      = (float*)alloc((size_t)N*64*4);
  float* as2     = (float*)alloc((size_t)N*4);
  float* ad2     = (float*)alloc((size_t)N*4);
  float* out2    = (float*)alloc((size_t)N*64*4);
  float* hid     = (float*)alloc((size_t)N*256*4);
  (void)ws_size; (void)n_in; (void)in_sizes; (void)out_size;

  hipMemsetAsync(deg, 0, (size_t)N*4, stream);

  const int tb = 256;
  count_deg_kernel<<<(TOT+tb-1)/tb, tb, 0, stream>>>(ei, deg, E, N);
  int nb = (N + SCAN_B - 1)/SCAN_B;                      // 196 <= 256
  scan1_kernel<<<nb, SCAN_B, 0, stream>>>(deg, rowptr, bsums, N);
  scan2_kernel<<<1, SCAN_B, 0, stream>>>(bsums, nb);
  scan3_kernel<<<nb, SCAN_B, 0, stream>>>(rowptr, bsums, cursor, N, TOT);
  fill_csr_kernel<<<(TOT+tb-1)/tb, tb, 0, stream>>>(ei, cursor, csr_src, E, N);

  dim3 blk(256);
  // GAT layer 1
  gemm_kernel<false,false><<<dim3((N+63)/64, 128/64), blk, 0, stream>>>(x, W1, nullptr, h1, N, 64, 128);
  alpha_kernel<128><<<(N*64+255)/256, 256, 0, stream>>>(h1, a1s, a1d, as1, ad1, N);
  gat_agg_kernel<128><<<(N*64+255)/256, 256, 0, stream>>>(rowptr, csr_src, h1, as1, ad1, b1, out1, N);
  // GAT layer 2
  gemm_kernel<false,false><<<dim3((N+63)/64, 64/64), blk, 0, stream>>>(out1, W2, nullptr, h2, N, 128, 64);
  alpha_kernel<64><<<(N*64+255)/256, 256, 0, stream>>>(h2, a2s, a2d, as2, ad2, N);
  gat_agg_kernel<64><<<(N*64+255)/256, 256, 0, stream>>>(rowptr, csr_src, h2, as2, ad2, b2, out2, N);
  // MLP
  gemm_kernel<true,true ><<<dim3((N+63)/64, 256/64), blk, 0, stream>>>(out2, Wm1, bm1, hid, N, 64, 256);
  gemm_kernel<true,false><<<dim3((N+63)/64, 256/64), blk, 0, stream>>>(hid, Wm2, bm2, out, N, 256, 256);
}

// Round 2
// 446.132 us; speedup vs baseline: 1.2628x; 1.2628x over previous
//
#include <hip/hip_runtime.h>
#include <math.h>

#define NNODES 50000
#define NEDGES 800000
#define SCAN_B 256

typedef __attribute__((ext_vector_type(8))) short short8v;
typedef __attribute__((ext_vector_type(4))) float f32x4;
typedef unsigned short ushort;

static __device__ __forceinline__ ushort f2bf(float f){
  union { float f; unsigned u; } v; v.f = f;
  unsigned r = (v.u + 0x7fffu + ((v.u >> 16) & 1u)) >> 16;   // RNE
  return (ushort)r;
}
static __device__ __forceinline__ float bf2f(ushort b){
  union { unsigned u; float f; } v; v.u = ((unsigned)b) << 16;
  return v.f;
}

// ---------------- CSR build ----------------

__global__ void count_deg_kernel(const int* __restrict__ ei, int* __restrict__ deg, int E, int n){
  int i = blockIdx.x*blockDim.x + threadIdx.x;
  if (i >= E + n) return;
  int d = (i < E) ? ei[E + i] : (i - E);
  atomicAdd(&deg[d], 1);
}

__global__ void scan1_kernel(const int* __restrict__ deg, int* __restrict__ rowptr,
                             int* __restrict__ bsums, int n){
  __shared__ int s[SCAN_B];
  int tid = threadIdx.x;
  int i = blockIdx.x*SCAN_B + tid;
  int v = (i < n) ? deg[i] : 0;
  s[tid] = v; __syncthreads();
  for (int off = 1; off < SCAN_B; off <<= 1){
    int t = (tid >= off) ? s[tid - off] : 0;
    __syncthreads();
    s[tid] += t;
    __syncthreads();
  }
  if (i < n) rowptr[i] = s[tid] - v;
  if (tid == SCAN_B-1) bsums[blockIdx.x] = s[tid];
}

__global__ void scan2_kernel(int* __restrict__ bsums, int nb){
  __shared__ int s[SCAN_B];
  int tid = threadIdx.x;
  int v = (tid < nb) ? bsums[tid] : 0;
  s[tid] = v; __syncthreads();
  for (int off = 1; off < SCAN_B; off <<= 1){
    int t = (tid >= off) ? s[tid - off] : 0;
    __syncthreads();
    s[tid] += t;
    __syncthreads();
  }
  if (tid < nb) bsums[tid] = s[tid] - v;
}

__global__ void scan3_kernel(int* __restrict__ rowptr, const int* __restrict__ bsums,
                             int* __restrict__ cursor, int n, int total){
  int i = blockIdx.x*SCAN_B + threadIdx.x;
  if (i < n){
    int r = rowptr[i] + bsums[blockIdx.x];
    rowptr[i] = r; cursor[i] = r;
  }
  if (i == 0) rowptr[n] = total;
}

__global__ void fill_csr_kernel(const int* __restrict__ ei, int* __restrict__ cursor,
                                int* __restrict__ csr_src, int E, int n){
  int i = blockIdx.x*blockDim.x + threadIdx.x;
  if (i >= E + n) return;
  int s, d;
  if (i < E){ s = ei[i]; d = ei[E+i]; } else { s = i - E; d = s; }
  int pos = atomicAdd(&cursor[d], 1);
  csr_src[pos] = s;
}

// ---------------- dtype conversion helpers ----------------

__global__ void f32_to_bf16_kernel(const float* __restrict__ in, ushort* __restrict__ out, int n4){
  int i = blockIdx.x*blockDim.x + threadIdx.x;
  if (i >= n4) return;
  float4 v = ((const float4*)in)[i];
  ushort4 o;
  o.x = f2bf(v.x); o.y = f2bf(v.y); o.z = f2bf(v.z); o.w = f2bf(v.w);
  ((ushort4*)out)[i] = o;
}

// W[k][n] f32  ->  Wt[n][k] bf16
__global__ void transpose_convert_kernel(const float* __restrict__ W, ushort* __restrict__ Wt,
                                         int K, int N){
  int i = blockIdx.x*blockDim.x + threadIdx.x;
  if (i >= K*N) return;
  int n = i / K, k = i - n*K;
  Wt[i] = f2bf(W[(size_t)k*N + n]);
}

// ---------------- bf16 MFMA GEMM: C[M][N] = A[M][K] @ Bt[N][K]^T ----------------
// 64x64 tile, BK=64, 256 thr = 4 waves (2x2), wave = 32x32 out.
// LDS XOR swizzle: 16B slot index ^= (row&7)  ->  frag ds_read_b128 conflict-free.

#define SWZ(row, byte_in_row) ((((row)*128) + (byte_in_row)) ^ (((row)&7) << 4))

template<bool BIAS, bool RELU, bool OUTBF16>
__global__ __launch_bounds__(256) void gemm_bf16_kernel(
    const ushort* __restrict__ A, const ushort* __restrict__ Bt,
    const float* __restrict__ bias, void* __restrict__ Cout,
    int M, int K, int N){
  __shared__ unsigned char lds[16384];      // As: [0,8K)  Bs: [8K,16K)
  const int tid = threadIdx.x;
  const int lane = tid & 63;
  const int wid = tid >> 6;
  const int wr = (wid >> 1) * 32;           // wave row offset in tile
  const int wc = (wid & 1) * 32;            // wave col offset in tile
  const int row0 = blockIdx.y * 64;
  const int col0 = blockIdx.x * 64;

  f32x4 acc[2][2];
  #pragma unroll
  for (int i = 0; i < 2; i++)
    #pragma unroll
    for (int j = 0; j < 2; j++)
      acc[i][j] = (f32x4){0.f, 0.f, 0.f, 0.f};

  const int lrow = lane & 15;
  const int kgrp = (lane >> 4) * 16;        // byte offset of this lane-group's k-octet

  for (int k0 = 0; k0 < K; k0 += 64){
    // stage A tile (64 rows x 64 k, bf16) — 512 16B-groups / 256 thr
    #pragma unroll
    for (int it = 0; it < 2; it++){
      int g = tid + it*256;
      int row = g >> 3, c8 = g & 7;
      int gr = row0 + row;
      uint4 v = {0u,0u,0u,0u};
      if (gr < M) v = *(const uint4*)(A + (size_t)gr*K + k0 + c8*8);
      *(uint4*)(lds + SWZ(row, c8*16)) = v;
    }
    // stage B tile (64 n-rows x 64 k)
    #pragma unroll
    for (int it = 0; it < 2; it++){
      int g = tid + it*256;
      int row = g >> 3, c8 = g & 7;
      uint4 v = *(const uint4*)(Bt + (size_t)(col0 + row)*K + k0 + c8*8);
      *(uint4*)(lds + 8192 + SWZ(row, c8*16)) = v;
    }
    __syncthreads();
    #pragma unroll
    for (int kb = 0; kb < 2; kb++){
      int kbyte = kb*64 + kgrp;
      short8v a[2], b[2];
      #pragma unroll
      for (int mi = 0; mi < 2; mi++)
        a[mi] = *(const short8v*)(lds + SWZ(wr + mi*16 + lrow, kbyte));
      #pragma unroll
      for (int ni = 0; ni < 2; ni++)
        b[ni] = *(const short8v*)(lds + 8192 + SWZ(wc + ni*16 + lrow, kbyte));
      #pragma unroll
      for (int mi = 0; mi < 2; mi++)
        #pragma unroll
        for (int ni = 0; ni < 2; ni++)
          acc[mi][ni] = __builtin_amdgcn_mfma_f32_16x16x32_bf16(a[mi], b[ni], acc[mi][ni], 0, 0, 0);
    }
    __syncthreads();
  }

  // epilogue: C/D layout col=lane&15, row=(lane>>4)*4+r
  #pragma unroll
  for (int mi = 0; mi < 2; mi++){
    #pragma unroll
    for (int ni = 0; ni < 2; ni++){
      int c = col0 + wc + ni*16 + (lane & 15);
      int rbase = row0 + wr + mi*16 + (lane >> 4)*4;
      float bv = BIAS ? bias[c] : 0.f;
      #pragma unroll
      for (int r = 0; r < 4; r++){
        int row = rbase + r;
        if (row >= M) continue;
        float v = acc[mi][ni][r] + bv;
        if (RELU) v = fmaxf(v, 0.f);
        if (OUTBF16) ((ushort*)Cout)[(size_t)row*N + c] = f2bf(v);
        else         ((float*)Cout)[(size_t)row*N + c] = v;
      }
    }
  }
}

// ---------------- per-node attention coefficients ----------------

template<int C>
__global__ void alpha_kernel(const ushort* __restrict__ h, const float* __restrict__ av_s,
                             const float* __restrict__ av_d, float* __restrict__ os,
                             float* __restrict__ od, int n){
  int gid = blockIdx.x*blockDim.x + threadIdx.x;
  int node = gid >> 6, lane = gid & 63;
  if (node >= n) return;
  constexpr int V = C/64;
  float ps = 0.f, pd = 0.f;
  #pragma unroll
  for (int j = 0; j < V; j++){
    int ch = lane*V + j;
    float hv = bf2f(h[(size_t)node*C + ch]);
    ps += hv * av_s[ch];
    pd += hv * av_d[ch];
  }
  #pragma unroll
  for (int off = 32; off > 0; off >>= 1){
    ps += __shfl_down(ps, off);
    pd += __shfl_down(pd, off);
  }
  if (lane == 0){ os[node] = ps; od[node] = pd; }
}

// ---------------- wave64 per dst: online segment-softmax + aggregate (+bias+relu) ----------------

template<int C>
__global__ void gat_agg_kernel(const int* __restrict__ rowptr, const int* __restrict__ csr_src,
                               const ushort* __restrict__ h, const float* __restrict__ as,
                               const float* __restrict__ ad, const float* __restrict__ bias,
                               ushort* __restrict__ out, int n){
  int gid = blockIdx.x*blockDim.x + threadIdx.x;
  int dst = gid >> 6, lane = gid & 63;
  if (dst >= n) return;
  constexpr int V = C/64;
  float adval = ad[dst];
  int r0 = rowptr[dst], r1 = rowptr[dst+1];
  float m = -INFINITY, denom = 0.f;
  float acc[V];
  #pragma unroll
  for (int v = 0; v < V; v++) acc[v] = 0.f;
  for (int j = r0; j < r1; ++j){
    int s = csr_src[j];
    float e = as[s] + adval;
    e = (e > 0.f) ? e : 0.2f*e;
    float mn = fmaxf(m, e);
    float scale = __expf(m - mn);
    float w = __expf(e - mn);
    denom = denom*scale + w;
    if (V == 2){
      unsigned hv = *(const unsigned*)(h + (size_t)s*C + lane*2);
      acc[0] = acc[0]*scale + w * bf2f((ushort)(hv & 0xffffu));
      acc[1] = acc[1]*scale + w * bf2f((ushort)(hv >> 16));
    } else {
      #pragma unroll
      for (int v = 0; v < V; v++)
        acc[v] = acc[v]*scale + w * bf2f(h[(size_t)s*C + lane*V + v]);
    }
    m = mn;
  }
  float inv = 1.f / denom;
  #pragma unroll
  for (int v = 0; v < V; v++){
    int ch = lane*V + v;
    float o = acc[v]*inv + bias[ch];
    out[(size_t)dst*C + ch] = f2bf(fmaxf(o, 0.f));
  }
}

// ---------------- launch ----------------

extern "C" void kernel_launch(void* const* d_in, const int* in_sizes, int n_in,
                              void* d_out, int out_size, void* d_ws, size_t ws_size,
                              hipStream_t stream){
  const float* x   = (const float*)d_in[0];
  const int*   ei  = (const int*)d_in[1];
  const float* W1  = (const float*)d_in[3];
  const float* a1s = (const float*)d_in[4];
  const float* a1d = (const float*)d_in[5];
  const float* b1  = (const float*)d_in[6];
  const float* W2  = (const float*)d_in[7];
  const float* a2s = (const float*)d_in[8];
  const float* a2d = (const float*)d_in[9];
  const float* b2  = (const float*)d_in[10];
  const float* Wm1 = (const float*)d_in[11];
  const float* bm1 = (const float*)d_in[12];
  const float* Wm2 = (const float*)d_in[13];
  const float* bm2 = (const float*)d_in[14];
  float* out = (float*)d_out;

  const int N = NNODES, E = NEDGES;
  const int TOT = E + N;

  char* w = (char*)d_ws;
  auto alloc = [&](size_t bytes)->void*{
    void* p = (void*)w;
    w += (bytes + 255) & ~(size_t)255;
    return p;
  };
  int*    deg     = (int*)alloc((size_t)N*4);
  int*    cursor  = (int*)alloc((size_t)N*4);
  int*    rowptr  = (int*)alloc((size_t)(N+1)*4);
  int*    bsums   = (int*)alloc(256*4);
  int*    csr_src = (int*)alloc((size_t)TOT*4);
  ushort* xb      = (ushort*)alloc((size_t)N*64*2);
  ushort* W1t     = (ushort*)alloc((size_t)64*128*2);
  ushort* W2t     = (ushort*)alloc((size_t)128*64*2);
  ushort* Wm1t    = (ushort*)alloc((size_t)64*256*2);
  ushort* Wm2t    = (ushort*)alloc((size_t)256*256*2);
  ushort* h1b     = (ushort*)alloc((size_t)N*128*2);
  float*  as1     = (float*)alloc((size_t)N*4);
  float*  ad1     = (float*)alloc((size_t)N*4);
  ushort* out1b   = (ushort*)alloc((size_t)N*128*2);
  ushort* h2b     = (ushort*)alloc((size_t)N*64*2);
  float*  as2     = (float*)alloc((size_t)N*4);
  float*  ad2     = (float*)alloc((size_t)N*4);
  ushort* out2b   = (ushort*)alloc((size_t)N*64*2);
  ushort* hidb    = (ushort*)alloc((size_t)N*256*2);
  (void)ws_size; (void)n_in; (void)in_sizes; (void)out_size;

  hipMemsetAsync(deg, 0, (size_t)N*4, stream);

  const int tb = 256;
  count_deg_kernel<<<(TOT+tb-1)/tb, tb, 0, stream>>>(ei, deg, E, N);
  int nb = (N + SCAN_B - 1)/SCAN_B;
  scan1_kernel<<<nb, SCAN_B, 0, stream>>>(deg, rowptr, bsums, N);
  scan2_kernel<<<1, SCAN_B, 0, stream>>>(bsums, nb);
  scan3_kernel<<<nb, SCAN_B, 0, stream>>>(rowptr, bsums, cursor, N, TOT);
  fill_csr_kernel<<<(TOT+tb-1)/tb, tb, 0, stream>>>(ei, cursor, csr_src, E, N);

  // conversions
  f32_to_bf16_kernel<<<(N*64/4+tb-1)/tb, tb, 0, stream>>>(x, xb, N*64/4);
  transpose_convert_kernel<<<(64*128+tb-1)/tb, tb, 0, stream>>>(W1, W1t, 64, 128);
  transpose_convert_kernel<<<(128*64+tb-1)/tb, tb, 0, stream>>>(W2, W2t, 128, 64);
  transpose_convert_kernel<<<(64*256+tb-1)/tb, tb, 0, stream>>>(Wm1, Wm1t, 64, 256);
  transpose_convert_kernel<<<(256*256+tb-1)/tb, tb, 0, stream>>>(Wm2, Wm2t, 256, 256);

  const int mb = (N + 63)/64;    // 782
  dim3 blk(256);
  // GAT layer 1
  gemm_bf16_kernel<false,false,true><<<dim3(128/64, mb), blk, 0, stream>>>(xb, W1t, nullptr, h1b, N, 64, 128);
  alpha_kernel<128><<<(N*64+255)/256, 256, 0, stream>>>(h1b, a1s, a1d, as1, ad1, N);
  gat_agg_kernel<128><<<(N*64+255)/256, 256, 0, stream>>>(rowptr, csr_src, h1b, as1, ad1, b1, out1b, N);
  // GAT layer 2
  gemm_bf16_kernel<false,false,true><<<dim3(64/64, mb), blk, 0, stream>>>(out1b, W2t, nullptr, h2b, N, 128, 64);
  alpha_kernel<64><<<(N*64+255)/256, 256, 0, stream>>>(h2b, a2s, a2d, as2, ad2, N);
  gat_agg_kernel<64><<<(N*64+255)/256, 256, 0, stream>>>(rowptr, csr_src, h2b, as2, ad2, b2, out2b, N);
  // MLP
  gemm_bf16_kernel<true,true ,true ><<<dim3(256/64, mb), blk, 0, stream>>>(out2b, Wm1t, bm1, hidb, N, 64, 256);
  gemm_bf16_kernel<true,false,false><<<dim3(256/64, mb), blk, 0, stream>>>(hidb, Wm2t, bm2, out, N, 256, 256);
}

// Round 3
// 405.988 us; speedup vs baseline: 1.3876x; 1.0989x over previous
//
#include <hip/hip_runtime.h>
#include <math.h>

#define NNODES 50000
#define NEDGES 800000
#define SCAN_B 256

typedef __attribute__((ext_vector_type(8))) short short8v;
typedef __attribute__((ext_vector_type(4))) float f32x4;
typedef unsigned short ushort;

static __device__ __forceinline__ ushort f2bf(float f){
  union { float f; unsigned u; } v; v.f = f;
  unsigned r = (v.u + 0x7fffu + ((v.u >> 16) & 1u)) >> 16;   // RNE
  return (ushort)r;
}
static __device__ __forceinline__ float bf2f(ushort b){
  union { unsigned u; float f; } v; v.u = ((unsigned)b) << 16;
  return v.f;
}

// ---------------- CSR build ----------------

__global__ void count_deg_kernel(const int* __restrict__ ei, int* __restrict__ deg, int E, int n){
  int i = blockIdx.x*blockDim.x + threadIdx.x;
  if (i >= E + n) return;
  int d = (i < E) ? ei[E + i] : (i - E);
  atomicAdd(&deg[d], 1);
}

__global__ void scan1_kernel(const int* __restrict__ deg, int* __restrict__ rowptr,
                             int* __restrict__ bsums, int n){
  __shared__ int s[SCAN_B];
  int tid = threadIdx.x;
  int i = blockIdx.x*SCAN_B + tid;
  int v = (i < n) ? deg[i] : 0;
  s[tid] = v; __syncthreads();
  for (int off = 1; off < SCAN_B; off <<= 1){
    int t = (tid >= off) ? s[tid - off] : 0;
    __syncthreads();
    s[tid] += t;
    __syncthreads();
  }
  if (i < n) rowptr[i] = s[tid] - v;
  if (tid == SCAN_B-1) bsums[blockIdx.x] = s[tid];
}

__global__ void scan2_kernel(int* __restrict__ bsums, int nb){
  __shared__ int s[SCAN_B];
  int tid = threadIdx.x;
  int v = (tid < nb) ? bsums[tid] : 0;
  s[tid] = v; __syncthreads();
  for (int off = 1; off < SCAN_B; off <<= 1){
    int t = (tid >= off) ? s[tid - off] : 0;
    __syncthreads();
    s[tid] += t;
    __syncthreads();
  }
  if (tid < nb) bsums[tid] = s[tid] - v;
}

__global__ void scan3_kernel(int* __restrict__ rowptr, const int* __restrict__ bsums,
                             int* __restrict__ cursor, int n, int total){
  int i = blockIdx.x*SCAN_B + threadIdx.x;
  if (i < n){
    int r = rowptr[i] + bsums[blockIdx.x];
    rowptr[i] = r; cursor[i] = r;
  }
  if (i == 0) rowptr[n] = total;
}

__global__ void fill_csr_kernel(const int* __restrict__ ei, int* __restrict__ cursor,
                                int* __restrict__ csr_src, int E, int n){
  int i = blockIdx.x*blockDim.x + threadIdx.x;
  if (i >= E + n) return;
  int s, d;
  if (i < E){ s = ei[i]; d = ei[E+i]; } else { s = i - E; d = s; }
  int pos = atomicAdd(&cursor[d], 1);
  csr_src[pos] = s;
}

// ---------------- folded attention vectors: u = W @ a_src, v = W @ a_dst ----------------

__global__ void vecs_kernel(const float* __restrict__ W1, const float* __restrict__ a1s,
                            const float* __restrict__ a1d,
                            const float* __restrict__ W2, const float* __restrict__ a2s,
                            const float* __restrict__ a2d,
                            float* __restrict__ u1, float* __restrict__ v1,
                            float* __restrict__ u2, float* __restrict__ v2){
  int t = threadIdx.x;
  if (t < 64){
    float su = 0.f, sv = 0.f;
    for (int c = 0; c < 128; c++){ float w = W1[t*128 + c]; su += w*a1s[c]; sv += w*a1d[c]; }
    u1[t] = su; v1[t] = sv;
  } else if (t < 192){
    int k = t - 64;
    float su = 0.f, sv = 0.f;
    for (int c = 0; c < 64; c++){ float w = W2[k*64 + c]; su += w*a2s[c]; sv += w*a2d[c]; }
    u2[k] = su; v2[k] = sv;
  }
}

// ---------------- x: f32 -> bf16, fused as1/ad1 = x . u1 / x . v1 ----------------

__global__ void prep_x_kernel(const float* __restrict__ x, const float* __restrict__ u1,
                              const float* __restrict__ v1, ushort* __restrict__ xb,
                              float* __restrict__ as1, float* __restrict__ ad1, int n){
  int gid = blockIdx.x*blockDim.x + threadIdx.x;
  int node = gid >> 6, lane = gid & 63;
  if (node >= n) return;
  float xv = x[(size_t)node*64 + lane];
  xb[(size_t)node*64 + lane] = f2bf(xv);
  float ps = xv * u1[lane], pd = xv * v1[lane];
  #pragma unroll
  for (int off = 32; off; off >>= 1){
    ps += __shfl_xor(ps, off);
    pd += __shfl_xor(pd, off);
  }
  if (lane == 0){ as1[node] = ps; ad1[node] = pd; }
}

// W[k][n] f32  ->  Wt[n][k] bf16
__global__ void transpose_convert_kernel(const float* __restrict__ W, ushort* __restrict__ Wt,
                                         int K, int N){
  int i = blockIdx.x*blockDim.x + threadIdx.x;
  if (i >= K*N) return;
  int n = i / K, k = i - n*K;
  Wt[i] = f2bf(W[(size_t)k*N + n]);
}

// ---------------- segment softmax over edges (wave per dst, edges across lanes) ----------------

__global__ void softmax_edges_kernel(const int* __restrict__ rowptr, const int* __restrict__ csr_src,
                                     const float* __restrict__ as, const float* __restrict__ ad,
                                     float* __restrict__ warr, float* __restrict__ dinv, int n){
  int gid = blockIdx.x*blockDim.x + threadIdx.x;
  int dst = gid >> 6, lane = gid & 63;
  if (dst >= n) return;
  int r0 = rowptr[dst], r1 = rowptr[dst+1];
  float adv = ad[dst];
  float m = -INFINITY;
  for (int j0 = r0; j0 < r1; j0 += 64){
    int j = j0 + lane;
    float e = -INFINITY;
    if (j < r1){
      int s = csr_src[j];
      e = as[s] + adv;
      e = (e > 0.f) ? e : 0.2f*e;
    }
    m = fmaxf(m, e);
  }
  #pragma unroll
  for (int off = 32; off; off >>= 1) m = fmaxf(m, __shfl_xor(m, off));
  float dsum = 0.f;
  for (int j0 = r0; j0 < r1; j0 += 64){
    int j = j0 + lane;
    if (j < r1){
      int s = csr_src[j];
      float e = as[s] + adv;
      e = (e > 0.f) ? e : 0.2f*e;
      float w = __expf(e - m);
      warr[j] = w;
      dsum += w;
    }
  }
  #pragma unroll
  for (int off = 32; off; off >>= 1) dsum += __shfl_xor(dsum, off);
  if (lane == 0) dinv[dst] = 1.f / dsum;
}

// ---------------- aggregation C=128: wave per dst, pure weighted gather-sum ----------------
// optionally fused next-layer alpha: as2 = out . u2, ad2 = out . v2

template<bool FUSE_ALPHA>
__global__ void agg128_kernel(const int* __restrict__ rowptr, const int* __restrict__ csr_src,
                              const ushort* __restrict__ h, const float* __restrict__ warr,
                              const float* __restrict__ dinv, const float* __restrict__ bias,
                              ushort* __restrict__ out,
                              const float* __restrict__ u2, const float* __restrict__ v2,
                              float* __restrict__ as2, float* __restrict__ ad2, int n){
  int gid = blockIdx.x*blockDim.x + threadIdx.x;
  int dst = gid >> 6, lane = gid & 63;
  if (dst >= n) return;
  int r0 = rowptr[dst], r1 = rowptr[dst+1];
  float acc0 = 0.f, acc1 = 0.f;
  int ch = lane*2;
  int j = r0;
  for (; j + 1 < r1; j += 2){
    float w0 = warr[j], w1 = warr[j+1];
    int s0 = csr_src[j], s1 = csr_src[j+1];
    unsigned hv0 = *(const unsigned*)(h + (size_t)s0*128 + ch);
    unsigned hv1 = *(const unsigned*)(h + (size_t)s1*128 + ch);
    acc0 += w0*bf2f((ushort)(hv0 & 0xffffu)) + w1*bf2f((ushort)(hv1 & 0xffffu));
    acc1 += w0*bf2f((ushort)(hv0 >> 16))     + w1*bf2f((ushort)(hv1 >> 16));
  }
  if (j < r1){
    float w0 = warr[j];
    int s0 = csr_src[j];
    unsigned hv0 = *(const unsigned*)(h + (size_t)s0*128 + ch);
    acc0 += w0*bf2f((ushort)(hv0 & 0xffffu));
    acc1 += w0*bf2f((ushort)(hv0 >> 16));
  }
  float inv = dinv[dst];
  float o0 = fmaxf(acc0*inv + bias[ch],   0.f);
  float o1 = fmaxf(acc1*inv + bias[ch+1], 0.f);
  unsigned pack = (unsigned)f2bf(o0) | ((unsigned)f2bf(o1) << 16);
  *(unsigned*)(out + (size_t)dst*128 + ch) = pack;
  if (FUSE_ALPHA){
    float ps = o0*u2[ch] + o1*u2[ch+1];
    float pd = o0*v2[ch] + o1*v2[ch+1];
    #pragma unroll
    for (int off = 32; off; off >>= 1){
      ps += __shfl_xor(ps, off);
      pd += __shfl_xor(pd, off);
    }
    if (lane == 0){ as2[dst] = ps; ad2[dst] = pd; }
  }
}

// ---------------- aggregation C=64: half-wave per edge (2 edges / iter) ----------------

__global__ void agg64_kernel(const int* __restrict__ rowptr, const int* __restrict__ csr_src,
                             const ushort* __restrict__ h, const float* __restrict__ warr,
                             const float* __restrict__ dinv, const float* __restrict__ bias,
                             ushort* __restrict__ out, int n){
  int gid = blockIdx.x*blockDim.x + threadIdx.x;
  int dst = gid >> 6, lane = gid & 63;
  if (dst >= n) return;
  int hw = lane >> 5, l5 = lane & 31;
  int r0 = rowptr[dst], r1 = rowptr[dst+1];
  float acc0 = 0.f, acc1 = 0.f;
  int ch = l5*2;
  for (int j0 = r0; j0 < r1; j0 += 2){
    int j = j0 + hw;
    if (j < r1){
      float w = warr[j];
      int s = csr_src[j];
      unsigned hv = *(const unsigned*)(h + (size_t)s*64 + ch);
      acc0 += w*bf2f((ushort)(hv & 0xffffu));
      acc1 += w*bf2f((ushort)(hv >> 16));
    }
  }
  acc0 += __shfl_xor(acc0, 32);
  acc1 += __shfl_xor(acc1, 32);
  if (lane < 32){
    float inv = dinv[dst];
    float o0 = fmaxf(acc0*inv + bias[ch],   0.f);
    float o1 = fmaxf(acc1*inv + bias[ch+1], 0.f);
    unsigned pack = (unsigned)f2bf(o0) | ((unsigned)f2bf(o1) << 16);
    *(unsigned*)(out + (size_t)dst*64 + ch) = pack;
  }
}

// ---------------- bf16 MFMA GEMM: C[M][N] = A[M][K] @ Bt[N][K]^T ----------------

#define SWZ(row, byte_in_row) ((((row)*128) + (byte_in_row)) ^ (((row)&7) << 4))

template<bool BIAS, bool RELU, bool OUTBF16>
__global__ __launch_bounds__(256) void gemm_bf16_kernel(
    const ushort* __restrict__ A, const ushort* __restrict__ Bt,
    const float* __restrict__ bias, void* __restrict__ Cout,
    int M, int K, int N){
  __shared__ unsigned char lds[16384];      // As: [0,8K)  Bs: [8K,16K)
  const int tid = threadIdx.x;
  const int lane = tid & 63;
  const int wid = tid >> 6;
  const int wr = (wid >> 1) * 32;
  const int wc = (wid & 1) * 32;
  const int row0 = blockIdx.y * 64;
  const int col0 = blockIdx.x * 64;

  f32x4 acc[2][2];
  #pragma unroll
  for (int i = 0; i < 2; i++)
    #pragma unroll
    for (int j = 0; j < 2; j++)
      acc[i][j] = (f32x4){0.f, 0.f, 0.f, 0.f};

  const int lrow = lane & 15;
  const int kgrp = (lane >> 4) * 16;

  for (int k0 = 0; k0 < K; k0 += 64){
    #pragma unroll
    for (int it = 0; it < 2; it++){
      int g = tid + it*256;
      int row = g >> 3, c8 = g & 7;
      int gr = row0 + row;
      uint4 v = {0u,0u,0u,0u};
      if (gr < M) v = *(const uint4*)(A + (size_t)gr*K + k0 + c8*8);
      *(uint4*)(lds + SWZ(row, c8*16)) = v;
    }
    #pragma unroll
    for (int it = 0; it < 2; it++){
      int g = tid + it*256;
      int row = g >> 3, c8 = g & 7;
      uint4 v = *(const uint4*)(Bt + (size_t)(col0 + row)*K + k0 + c8*8);
      *(uint4*)(lds + 8192 + SWZ(row, c8*16)) = v;
    }
    __syncthreads();
    #pragma unroll
    for (int kb = 0; kb < 2; kb++){
      int kbyte = kb*64 + kgrp;
      short8v a[2], b[2];
      #pragma unroll
      for (int mi = 0; mi < 2; mi++)
        a[mi] = *(const short8v*)(lds + SWZ(wr + mi*16 + lrow, kbyte));
      #pragma unroll
      for (int ni = 0; ni < 2; ni++)
        b[ni] = *(const short8v*)(lds + 8192 + SWZ(wc + ni*16 + lrow, kbyte));
      #pragma unroll
      for (int mi = 0; mi < 2; mi++)
        #pragma unroll
        for (int ni = 0; ni < 2; ni++)
          acc[mi][ni] = __builtin_amdgcn_mfma_f32_16x16x32_bf16(a[mi], b[ni], acc[mi][ni], 0, 0, 0);
    }
    __syncthreads();
  }

  #pragma unroll
  for (int mi = 0; mi < 2; mi++){
    #pragma unroll
    for (int ni = 0; ni < 2; ni++){
      int c = col0 + wc + ni*16 + (lane & 15);
      int rbase = row0 + wr + mi*16 + (lane >> 4)*4;
      float bv = BIAS ? bias[c] : 0.f;
      #pragma unroll
      for (int r = 0; r < 4; r++){
        int row = rbase + r;
        if (row >= M) continue;
        float v = acc[mi][ni][r] + bv;
        if (RELU) v = fmaxf(v, 0.f);
        if (OUTBF16) ((ushort*)Cout)[(size_t)row*N + c] = f2bf(v);
        else         ((float*)Cout)[(size_t)row*N + c] = v;
      }
    }
  }
}

// ---------------- launch ----------------

extern "C" void kernel_launch(void* const* d_in, const int* in_sizes, int n_in,
                              void* d_out, int out_size, void* d_ws, size_t ws_size,
                              hipStream_t stream){
  const float* x   = (const float*)d_in[0];
  const int*   ei  = (const int*)d_in[1];
  const float* W1  = (const float*)d_in[3];
  const float* a1s = (const float*)d_in[4];
  const float* a1d = (const float*)d_in[5];
  const float* b1  = (const float*)d_in[6];
  const float* W2  = (const float*)d_in[7];
  const float* a2s = (const float*)d_in[8];
  const float* a2d = (const float*)d_in[9];
  const float* b2  = (const float*)d_in[10];
  const float* Wm1 = (const float*)d_in[11];
  const float* bm1 = (const float*)d_in[12];
  const float* Wm2 = (const float*)d_in[13];
  const float* bm2 = (const float*)d_in[14];
  float* out = (float*)d_out;

  const int N = NNODES, E = NEDGES;
  const int TOT = E + N;

  char* w = (char*)d_ws;
  auto alloc = [&](size_t bytes)->void*{
    void* p = (void*)w;
    w += (bytes + 255) & ~(size_t)255;
    return p;
  };
  int*    deg     = (int*)alloc((size_t)N*4);
  int*    cursor  = (int*)alloc((size_t)N*4);
  int*    rowptr  = (int*)alloc((size_t)(N+1)*4);
  int*    bsums   = (int*)alloc(256*4);
  int*    csr_src = (int*)alloc((size_t)TOT*4);
  ushort* xb      = (ushort*)alloc((size_t)N*64*2);
  ushort* W1t     = (ushort*)alloc((size_t)64*128*2);
  ushort* W2t     = (ushort*)alloc((size_t)128*64*2);
  ushort* Wm1t    = (ushort*)alloc((size_t)64*256*2);
  ushort* Wm2t    = (ushort*)alloc((size_t)256*256*2);
  float*  u1      = (float*)alloc(64*4);
  float*  v1      = (float*)alloc(64*4);
  float*  u2      = (float*)alloc(128*4);
  float*  v2      = (float*)alloc(128*4);
  ushort* h1b     = (ushort*)alloc((size_t)N*128*2);
  float*  as1     = (float*)alloc((size_t)N*4);
  float*  ad1     = (float*)alloc((size_t)N*4);
  float*  w1arr   = (float*)alloc((size_t)TOT*4);
  float*  dinv1   = (float*)alloc((size_t)N*4);
  ushort* out1b   = (ushort*)alloc((size_t)N*128*2);
  ushort* h2b     = (ushort*)alloc((size_t)N*64*2);
  float*  as2     = (float*)alloc((size_t)N*4);
  float*  ad2     = (float*)alloc((size_t)N*4);
  float*  w2arr   = (float*)alloc((size_t)TOT*4);
  float*  dinv2   = (float*)alloc((size_t)N*4);
  ushort* out2b   = (ushort*)alloc((size_t)N*64*2);
  ushort* hidb    = (ushort*)alloc((size_t)N*256*2);
  (void)ws_size; (void)n_in; (void)in_sizes; (void)out_size;

  hipMemsetAsync(deg, 0, (size_t)N*4, stream);

  const int tb = 256;
  count_deg_kernel<<<(TOT+tb-1)/tb, tb, 0, stream>>>(ei, deg, E, N);
  int nb = (N + SCAN_B - 1)/SCAN_B;
  scan1_kernel<<<nb, SCAN_B, 0, stream>>>(deg, rowptr, bsums, N);
  scan2_kernel<<<1, SCAN_B, 0, stream>>>(bsums, nb);
  scan3_kernel<<<nb, SCAN_B, 0, stream>>>(rowptr, bsums, cursor, N, TOT);
  fill_csr_kernel<<<(TOT+tb-1)/tb, tb, 0, stream>>>(ei, cursor, csr_src, E, N);

  vecs_kernel<<<1, 192, 0, stream>>>(W1, a1s, a1d, W2, a2s, a2d, u1, v1, u2, v2);
  prep_x_kernel<<<(N*64+255)/256, 256, 0, stream>>>(x, u1, v1, xb, as1, ad1, N);
  transpose_convert_kernel<<<(64*128+tb-1)/tb, tb, 0, stream>>>(W1, W1t, 64, 128);
  transpose_convert_kernel<<<(128*64+tb-1)/tb, tb, 0, stream>>>(W2, W2t, 128, 64);
  transpose_convert_kernel<<<(64*256+tb-1)/tb, tb, 0, stream>>>(Wm1, Wm1t, 64, 256);
  transpose_convert_kernel<<<(256*256+tb-1)/tb, tb, 0, stream>>>(Wm2, Wm2t, 256, 256);

  const int mb = (N + 63)/64;
  dim3 blk(256);
  const int nwave = (N*64 + 255)/256;

  // GAT layer 1
  softmax_edges_kernel<<<nwave, 256, 0, stream>>>(rowptr, csr_src, as1, ad1, w1arr, dinv1, N);
  gemm_bf16_kernel<false,false,true><<<dim3(128/64, mb), blk, 0, stream>>>(xb, W1t, nullptr, h1b, N, 64, 128);
  agg128_kernel<true><<<nwave, 256, 0, stream>>>(rowptr, csr_src, h1b, w1arr, dinv1, b1,
                                                 out1b, u2, v2, as2, ad2, N);
  // GAT layer 2
  softmax_edges_kernel<<<nwave, 256, 0, stream>>>(rowptr, csr_src, as2, ad2, w2arr, dinv2, N);
  gemm_bf16_kernel<false,false,true><<<dim3(64/64, mb), blk, 0, stream>>>(out1b, W2t, nullptr, h2b, N, 128, 64);
  agg64_kernel<<<nwave, 256, 0, stream>>>(rowptr, csr_src, h2b, w2arr, dinv2, b2, out2b, N);
  // MLP
  gemm_bf16_kernel<true,true ,true ><<<dim3(256/64, mb), blk, 0, stream>>>(out2b, Wm1t, bm1, hidb, N, 64, 256);
  gemm_bf16_kernel<true,false,false><<<dim3(256/64, mb), blk, 0, stream>>>(hidb, Wm2t, bm2, out, N, 256, 256);
}

// Round 4
// 337.531 us; speedup vs baseline: 1.6690x; 1.2028x over previous
//
#include <hip/hip_runtime.h>
#include <math.h>

#define NNODES 50000
#define NEDGES 800000
#define SCAN_B 256

typedef __attribute__((ext_vector_type(8))) short short8v;
typedef __attribute__((ext_vector_type(4))) float f32x4;
typedef unsigned short ushort;

static __device__ __forceinline__ ushort f2bf(float f){
  union { float f; unsigned u; } v; v.f = f;
  unsigned r = (v.u + 0x7fffu + ((v.u >> 16) & 1u)) >> 16;   // RNE
  return (ushort)r;
}
static __device__ __forceinline__ float bf2f(ushort b){
  union { unsigned u; float f; } v; v.u = ((unsigned)b) << 16;
  return v.f;
}
static __device__ __forceinline__ float rl_f(float v, int l){
  return __int_as_float(__builtin_amdgcn_readlane(__float_as_int(v), l));
}
static __device__ __forceinline__ int rl_i(int v, int l){
  return __builtin_amdgcn_readlane(v, l);
}

// ---------------- CSR build ----------------

__global__ void count_deg_kernel(const int* __restrict__ ei, int* __restrict__ deg, int E, int n){
  int i = blockIdx.x*blockDim.x + threadIdx.x;
  if (i >= E + n) return;
  int d = (i < E) ? ei[E + i] : (i - E);
  atomicAdd(&deg[d], 1);
}

__global__ void scan1_kernel(const int* __restrict__ deg, int* __restrict__ rowptr,
                             int* __restrict__ bsums, int n){
  __shared__ int s[SCAN_B];
  int tid = threadIdx.x;
  int i = blockIdx.x*SCAN_B + tid;
  int v = (i < n) ? deg[i] : 0;
  s[tid] = v; __syncthreads();
  for (int off = 1; off < SCAN_B; off <<= 1){
    int t = (tid >= off) ? s[tid - off] : 0;
    __syncthreads();
    s[tid] += t;
    __syncthreads();
  }
  if (i < n) rowptr[i] = s[tid] - v;
  if (tid == SCAN_B-1) bsums[blockIdx.x] = s[tid];
}

__global__ void scan2_kernel(int* __restrict__ bsums, int nb){
  __shared__ int s[SCAN_B];
  int tid = threadIdx.x;
  int v = (tid < nb) ? bsums[tid] : 0;
  s[tid] = v; __syncthreads();
  for (int off = 1; off < SCAN_B; off <<= 1){
    int t = (tid >= off) ? s[tid - off] : 0;
    __syncthreads();
    s[tid] += t;
    __syncthreads();
  }
  if (tid < nb) bsums[tid] = s[tid] - v;
}

__global__ void scan3_kernel(int* __restrict__ rowptr, const int* __restrict__ bsums,
                             int* __restrict__ cursor, int n, int total){
  int i = blockIdx.x*SCAN_B + threadIdx.x;
  if (i < n){
    int r = rowptr[i] + bsums[blockIdx.x];
    rowptr[i] = r; cursor[i] = r;
  }
  if (i == 0) rowptr[n] = total;
}

__global__ void fill_csr_kernel(const int* __restrict__ ei, int* __restrict__ cursor,
                                int* __restrict__ csr_src, int E, int n){
  int i = blockIdx.x*blockDim.x + threadIdx.x;
  if (i >= E + n) return;
  int s, d;
  if (i < E){ s = ei[i]; d = ei[E+i]; } else { s = i - E; d = s; }
  int pos = atomicAdd(&cursor[d], 1);
  csr_src[pos] = s;
}

// ---------------- folded attention vectors: u = W @ a_src, v = W @ a_dst ----------------

__global__ void vecs_kernel(const float* __restrict__ W1, const float* __restrict__ a1s,
                            const float* __restrict__ a1d,
                            const float* __restrict__ W2, const float* __restrict__ a2s,
                            const float* __restrict__ a2d,
                            float* __restrict__ u1, float* __restrict__ v1,
                            float* __restrict__ u2, float* __restrict__ v2){
  int t = threadIdx.x;
  if (t < 64){
    float su = 0.f, sv = 0.f;
    for (int c = 0; c < 128; c++){ float w = W1[t*128 + c]; su += w*a1s[c]; sv += w*a1d[c]; }
    u1[t] = su; v1[t] = sv;
  } else if (t < 192){
    int k = t - 64;
    float su = 0.f, sv = 0.f;
    for (int c = 0; c < 64; c++){ float w = W2[k*64 + c]; su += w*a2s[c]; sv += w*a2d[c]; }
    u2[k] = su; v2[k] = sv;
  }
}

// ---------------- x: f32 -> bf16, fused as1/ad1 = x . u1 / x . v1 ----------------

__global__ void prep_x_kernel(const float* __restrict__ x, const float* __restrict__ u1,
                              const float* __restrict__ v1, ushort* __restrict__ xb,
                              float* __restrict__ as1, float* __restrict__ ad1, int n){
  int gid = blockIdx.x*blockDim.x + threadIdx.x;
  int node = gid >> 6, lane = gid & 63;
  if (node >= n) return;
  float xv = x[(size_t)node*64 + lane];
  xb[(size_t)node*64 + lane] = f2bf(xv);
  float ps = xv * u1[lane], pd = xv * v1[lane];
  #pragma unroll
  for (int off = 32; off; off >>= 1){
    ps += __shfl_xor(ps, off);
    pd += __shfl_xor(pd, off);
  }
  if (lane == 0){ as1[node] = ps; ad1[node] = pd; }
}

// ---------------- all weight transposes+converts in one kernel ----------------
// W[k][n] f32 -> Wt[n][k] bf16.  ranges: W1 64x128 | W2 128x64 | Wm1 64x256 | Wm2 256x256

__global__ void transpose_all_kernel(const float* __restrict__ W1, const float* __restrict__ W2,
                                     const float* __restrict__ Wm1, const float* __restrict__ Wm2,
                                     ushort* __restrict__ W1t, ushort* __restrict__ W2t,
                                     ushort* __restrict__ Wm1t, ushort* __restrict__ Wm2t){
  int i = blockIdx.x*blockDim.x + threadIdx.x;
  if (i < 8192){
    int k = i & 63;  int nn = i >> 6;          // wait: layout below
    // W1t[n][k], N=128, K=64: i = n*64 + k
    int n_ = i >> 6, k_ = i & 63;
    W1t[i] = f2bf(W1[(size_t)k_*128 + n_]);
    (void)k; (void)nn;
  } else if (i < 16384){
    int j = i - 8192;                           // W2t[n][k], N=64, K=128
    int n_ = j >> 7, k_ = j & 127;
    W2t[j] = f2bf(W2[(size_t)k_*64 + n_]);
  } else if (i < 32768){
    int j = i - 16384;                          // Wm1t[n][k], N=256, K=64
    int n_ = j >> 6, k_ = j & 63;
    Wm1t[j] = f2bf(Wm1[(size_t)k_*256 + n_]);
  } else if (i < 98304){
    int j = i - 32768;                          // Wm2t[n][k], N=256, K=256
    int n_ = j >> 8, k_ = j & 255;
    Wm2t[j] = f2bf(Wm2[(size_t)k_*256 + n_]);
  }
}

// ---------------- fused GAT aggregation, C=128 (wave per dst) ----------------
// chunk-of-64-edges softmax in lanes, then readlane-broadcast weighted gather-sum.
// optionally fuses next-layer alpha: as2 = out . u2, ad2 = out . v2

template<bool FUSE_ALPHA>
__global__ void agg128_fused_kernel(const int* __restrict__ rowptr, const int* __restrict__ csr_src,
                                    const ushort* __restrict__ h, const float* __restrict__ as,
                                    const float* __restrict__ ad, const float* __restrict__ bias,
                                    ushort* __restrict__ out,
                                    const float* __restrict__ u2, const float* __restrict__ v2,
                                    float* __restrict__ as2, float* __restrict__ ad2, int n){
  int gid = blockIdx.x*blockDim.x + threadIdx.x;
  int dst = gid >> 6, lane = gid & 63;
  if (dst >= n) return;
  int r0 = rowptr[dst], r1 = rowptr[dst+1];
  float adv = ad[dst];
  float m = -INFINITY, denom = 0.f, acc0 = 0.f, acc1 = 0.f;
  int ch = lane*2;
  for (int j0 = r0; j0 < r1; j0 += 64){
    int j = j0 + lane;
    int cnt = min(64, r1 - j0);
    bool valid = (j < r1);
    int s = valid ? csr_src[j] : 0;
    float e = -INFINITY;
    if (valid){
      e = as[s] + adv;
      e = (e > 0.f) ? e : 0.2f*e;
    }
    float cm = e;
    #pragma unroll
    for (int off = 32; off; off >>= 1) cm = fmaxf(cm, __shfl_xor(cm, off));
    float mn = fmaxf(m, cm);
    float w = valid ? __expf(e - mn) : 0.f;
    float csum = w;
    #pragma unroll
    for (int off = 32; off; off >>= 1) csum += __shfl_xor(csum, off);
    float scale = __expf(m - mn);          // first chunk: exp(-inf)=0
    denom = denom*scale + csum;
    acc0 *= scale; acc1 *= scale;
    m = mn;
    int k = 0;
    for (; k + 3 < cnt; k += 4){
      float w0 = rl_f(w,k), w1 = rl_f(w,k+1), w2 = rl_f(w,k+2), w3 = rl_f(w,k+3);
      int   s0 = rl_i(s,k), s1 = rl_i(s,k+1), s2 = rl_i(s,k+2), s3 = rl_i(s,k+3);
      unsigned h0 = *(const unsigned*)(h + (size_t)s0*128 + ch);
      unsigned h1 = *(const unsigned*)(h + (size_t)s1*128 + ch);
      unsigned h2 = *(const unsigned*)(h + (size_t)s2*128 + ch);
      unsigned h3 = *(const unsigned*)(h + (size_t)s3*128 + ch);
      acc0 += w0*bf2f((ushort)(h0 & 0xffffu)) + w1*bf2f((ushort)(h1 & 0xffffu))
            + w2*bf2f((ushort)(h2 & 0xffffu)) + w3*bf2f((ushort)(h3 & 0xffffu));
      acc1 += w0*bf2f((ushort)(h0 >> 16)) + w1*bf2f((ushort)(h1 >> 16))
            + w2*bf2f((ushort)(h2 >> 16)) + w3*bf2f((ushort)(h3 >> 16));
    }
    for (; k < cnt; k++){
      float wk = rl_f(w,k); int sk = rl_i(s,k);
      unsigned hv = *(const unsigned*)(h + (size_t)sk*128 + ch);
      acc0 += wk*bf2f((ushort)(hv & 0xffffu));
      acc1 += wk*bf2f((ushort)(hv >> 16));
    }
  }
  float inv = 1.f / denom;
  float o0 = fmaxf(acc0*inv + bias[ch],   0.f);
  float o1 = fmaxf(acc1*inv + bias[ch+1], 0.f);
  unsigned pack = (unsigned)f2bf(o0) | ((unsigned)f2bf(o1) << 16);
  *(unsigned*)(out + (size_t)dst*128 + ch) = pack;
  if (FUSE_ALPHA){
    float ps = o0*u2[ch] + o1*u2[ch+1];
    float pd = o0*v2[ch] + o1*v2[ch+1];
    #pragma unroll
    for (int off = 32; off; off >>= 1){
      ps += __shfl_xor(ps, off);
      pd += __shfl_xor(pd, off);
    }
    if (lane == 0){ as2[dst] = ps; ad2[dst] = pd; }
  }
}

// ---------------- fused GAT aggregation, C=64 (wave per dst, 1 ch/lane) ----------------

__global__ void agg64_fused_kernel(const int* __restrict__ rowptr, const int* __restrict__ csr_src,
                                   const ushort* __restrict__ h, const float* __restrict__ as,
                                   const float* __restrict__ ad, const float* __restrict__ bias,
                                   ushort* __restrict__ out, int n){
  int gid = blockIdx.x*blockDim.x + threadIdx.x;
  int dst = gid >> 6, lane = gid & 63;
  if (dst >= n) return;
  int r0 = rowptr[dst], r1 = rowptr[dst+1];
  float adv = ad[dst];
  float m = -INFINITY, denom = 0.f, acc = 0.f;
  for (int j0 = r0; j0 < r1; j0 += 64){
    int j = j0 + lane;
    int cnt = min(64, r1 - j0);
    bool valid = (j < r1);
    int s = valid ? csr_src[j] : 0;
    float e = -INFINITY;
    if (valid){
      e = as[s] + adv;
      e = (e > 0.f) ? e : 0.2f*e;
    }
    float cm = e;
    #pragma unroll
    for (int off = 32; off; off >>= 1) cm = fmaxf(cm, __shfl_xor(cm, off));
    float mn = fmaxf(m, cm);
    float w = valid ? __expf(e - mn) : 0.f;
    float csum = w;
    #pragma unroll
    for (int off = 32; off; off >>= 1) csum += __shfl_xor(csum, off);
    float scale = __expf(m - mn);
    denom = denom*scale + csum;
    acc *= scale;
    m = mn;
    int k = 0;
    for (; k + 3 < cnt; k += 4){
      float w0 = rl_f(w,k), w1 = rl_f(w,k+1), w2 = rl_f(w,k+2), w3 = rl_f(w,k+3);
      int   s0 = rl_i(s,k), s1 = rl_i(s,k+1), s2 = rl_i(s,k+2), s3 = rl_i(s,k+3);
      float h0 = bf2f(h[(size_t)s0*64 + lane]);
      float h1 = bf2f(h[(size_t)s1*64 + lane]);
      float h2 = bf2f(h[(size_t)s2*64 + lane]);
      float h3 = bf2f(h[(size_t)s3*64 + lane]);
      acc += w0*h0 + w1*h1 + w2*h2 + w3*h3;
    }
    for (; k < cnt; k++){
      float wk = rl_f(w,k); int sk = rl_i(s,k);
      acc += wk*bf2f(h[(size_t)sk*64 + lane]);
    }
  }
  float inv = 1.f / denom;
  float o = fmaxf(acc*inv + bias[lane], 0.f);
  out[(size_t)dst*64 + lane] = f2bf(o);
}

// ---------------- bf16 MFMA GEMM: C[M][N] = A[M][K] @ Bt[N][K]^T ----------------

#define SWZ(row, byte_in_row) ((((row)*128) + (byte_in_row)) ^ (((row)&7) << 4))

template<bool BIAS, bool RELU, bool OUTBF16>
__global__ __launch_bounds__(256) void gemm_bf16_kernel(
    const ushort* __restrict__ A, const ushort* __restrict__ Bt,
    const float* __restrict__ bias, void* __restrict__ Cout,
    int M, int K, int N){
  __shared__ unsigned char lds[16384];      // As: [0,8K)  Bs: [8K,16K)
  const int tid = threadIdx.x;
  const int lane = tid & 63;
  const int wid = tid >> 6;
  const int wr = (wid >> 1) * 32;
  const int wc = (wid & 1) * 32;
  const int row0 = blockIdx.y * 64;
  const int col0 = blockIdx.x * 64;

  f32x4 acc[2][2];
  #pragma unroll
  for (int i = 0; i < 2; i++)
    #pragma unroll
    for (int j = 0; j < 2; j++)
      acc[i][j] = (f32x4){0.f, 0.f, 0.f, 0.f};

  const int lrow = lane & 15;
  const int kgrp = (lane >> 4) * 16;

  for (int k0 = 0; k0 < K; k0 += 64){
    #pragma unroll
    for (int it = 0; it < 2; it++){
      int g = tid + it*256;
      int row = g >> 3, c8 = g & 7;
      int gr = row0 + row;
      uint4 v = {0u,0u,0u,0u};
      if (gr < M) v = *(const uint4*)(A + (size_t)gr*K + k0 + c8*8);
      *(uint4*)(lds + SWZ(row, c8*16)) = v;
    }
    #pragma unroll
    for (int it = 0; it < 2; it++){
      int g = tid + it*256;
      int row = g >> 3, c8 = g & 7;
      uint4 v = *(const uint4*)(Bt + (size_t)(col0 + row)*K + k0 + c8*8);
      *(uint4*)(lds + 8192 + SWZ(row, c8*16)) = v;
    }
    __syncthreads();
    #pragma unroll
    for (int kb = 0; kb < 2; kb++){
      int kbyte = kb*64 + kgrp;
      short8v a[2], b[2];
      #pragma unroll
      for (int mi = 0; mi < 2; mi++)
        a[mi] = *(const short8v*)(lds + SWZ(wr + mi*16 + lrow, kbyte));
      #pragma unroll
      for (int ni = 0; ni < 2; ni++)
        b[ni] = *(const short8v*)(lds + 8192 + SWZ(wc + ni*16 + lrow, kbyte));
      #pragma unroll
      for (int mi = 0; mi < 2; mi++)
        #pragma unroll
        for (int ni = 0; ni < 2; ni++)
          acc[mi][ni] = __builtin_amdgcn_mfma_f32_16x16x32_bf16(a[mi], b[ni], acc[mi][ni], 0, 0, 0);
    }
    __syncthreads();
  }

  #pragma unroll
  for (int mi = 0; mi < 2; mi++){
    #pragma unroll
    for (int ni = 0; ni < 2; ni++){
      int c = col0 + wc + ni*16 + (lane & 15);
      int rbase = row0 + wr + mi*16 + (lane >> 4)*4;
      float bv = BIAS ? bias[c] : 0.f;
      #pragma unroll
      for (int r = 0; r < 4; r++){
        int row = rbase + r;
        if (row >= M) continue;
        float v = acc[mi][ni][r] + bv;
        if (RELU) v = fmaxf(v, 0.f);
        if (OUTBF16) ((ushort*)Cout)[(size_t)row*N + c] = f2bf(v);
        else         ((float*)Cout)[(size_t)row*N + c] = v;
      }
    }
  }
}

// ---------------- launch ----------------

extern "C" void kernel_launch(void* const* d_in, const int* in_sizes, int n_in,
                              void* d_out, int out_size, void* d_ws, size_t ws_size,
                              hipStream_t stream){
  const float* x   = (const float*)d_in[0];
  const int*   ei  = (const int*)d_in[1];
  const float* W1  = (const float*)d_in[3];
  const float* a1s = (const float*)d_in[4];
  const float* a1d = (const float*)d_in[5];
  const float* b1  = (const float*)d_in[6];
  const float* W2  = (const float*)d_in[7];
  const float* a2s = (const float*)d_in[8];
  const float* a2d = (const float*)d_in[9];
  const float* b2  = (const float*)d_in[10];
  const float* Wm1 = (const float*)d_in[11];
  const float* bm1 = (const float*)d_in[12];
  const float* Wm2 = (const float*)d_in[13];
  const float* bm2 = (const float*)d_in[14];
  float* out = (float*)d_out;

  const int N = NNODES, E = NEDGES;
  const int TOT = E + N;

  char* w = (char*)d_ws;
  auto alloc = [&](size_t bytes)->void*{
    void* p = (void*)w;
    w += (bytes + 255) & ~(size_t)255;
    return p;
  };
  int*    deg     = (int*)alloc((size_t)N*4);
  int*    cursor  = (int*)alloc((size_t)N*4);
  int*    rowptr  = (int*)alloc((size_t)(N+1)*4);
  int*    bsums   = (int*)alloc(256*4);
  int*    csr_src = (int*)alloc((size_t)TOT*4);
  ushort* xb      = (ushort*)alloc((size_t)N*64*2);
  ushort* W1t     = (ushort*)alloc((size_t)64*128*2);
  ushort* W2t     = (ushort*)alloc((size_t)128*64*2);
  ushort* Wm1t    = (ushort*)alloc((size_t)64*256*2);
  ushort* Wm2t    = (ushort*)alloc((size_t)256*256*2);
  float*  u1      = (float*)alloc(64*4);
  float*  v1      = (float*)alloc(64*4);
  float*  u2      = (float*)alloc(128*4);
  float*  v2      = (float*)alloc(128*4);
  ushort* h1b     = (ushort*)alloc((size_t)N*128*2);
  float*  as1     = (float*)alloc((size_t)N*4);
  float*  ad1     = (float*)alloc((size_t)N*4);
  ushort* out1b   = (ushort*)alloc((size_t)N*128*2);
  ushort* h2b     = (ushort*)alloc((size_t)N*64*2);
  float*  as2     = (float*)alloc((size_t)N*4);
  float*  ad2     = (float*)alloc((size_t)N*4);
  ushort* out2b   = (ushort*)alloc((size_t)N*64*2);
  ushort* hidb    = (ushort*)alloc((size_t)N*256*2);
  (void)ws_size; (void)n_in; (void)in_sizes; (void)out_size;

  hipMemsetAsync(deg, 0, (size_t)N*4, stream);

  const int tb = 256;
  count_deg_kernel<<<(TOT+tb-1)/tb, tb, 0, stream>>>(ei, deg, E, N);
  int nb = (N + SCAN_B - 1)/SCAN_B;
  scan1_kernel<<<nb, SCAN_B, 0, stream>>>(deg, rowptr, bsums, N);
  scan2_kernel<<<1, SCAN_B, 0, stream>>>(bsums, nb);
  scan3_kernel<<<nb, SCAN_B, 0, stream>>>(rowptr, bsums, cursor, N, TOT);
  fill_csr_kernel<<<(TOT+tb-1)/tb, tb, 0, stream>>>(ei, cursor, csr_src, E, N);

  vecs_kernel<<<1, 192, 0, stream>>>(W1, a1s, a1d, W2, a2s, a2d, u1, v1, u2, v2);
  prep_x_kernel<<<(N*64+255)/256, 256, 0, stream>>>(x, u1, v1, xb, as1, ad1, N);
  transpose_all_kernel<<<(98304+tb-1)/tb, tb, 0, stream>>>(W1, W2, Wm1, Wm2, W1t, W2t, Wm1t, Wm2t);

  const int mb = (N + 63)/64;
  dim3 blk(256);
  const int nwave = (N*64 + 255)/256;

  // GAT layer 1
  gemm_bf16_kernel<false,false,true><<<dim3(128/64, mb), blk, 0, stream>>>(xb, W1t, nullptr, h1b, N, 64, 128);
  agg128_fused_kernel<true><<<nwave, 256, 0, stream>>>(rowptr, csr_src, h1b, as1, ad1, b1,
                                                       out1b, u2, v2, as2, ad2, N);
  // GAT layer 2
  gemm_bf16_kernel<false,false,true><<<dim3(64/64, mb), blk, 0, stream>>>(out1b, W2t, nullptr, h2b, N, 128, 64);
  agg64_fused_kernel<<<nwave, 256, 0, stream>>>(rowptr, csr_src, h2b, as2, ad2, b2, out2b, N);
  // MLP
  gemm_bf16_kernel<true,true ,true ><<<dim3(256/64, mb), blk, 0, stream>>>(out2b, Wm1t, bm1, hidb, N, 64, 256);
  gemm_bf16_kernel<true,false,false><<<dim3(256/64, mb), blk, 0, stream>>>(hidb, Wm2t, bm2, out, N, 256, 256);
}

// Round 5
// 263.070 us; speedup vs baseline: 2.1415x; 1.2830x over previous
//
#include <hip/hip_runtime.h>
#include <math.h>

#define NNODES 50000
#define NEDGES 800000
#define NBUCK  256          // buckets = dst >> 8 ; used: ceil(50000/256) = 196
#define NBUCK_USED ((NNODES + 255) >> 8)
#define CAP    6144         // max edges per bucket (mean 4352, sd ~66 -> 27 sigma margin)
#define PB_EDGES 4096       // edges per bin_edges block

typedef __attribute__((ext_vector_type(8))) short short8v;
typedef __attribute__((ext_vector_type(4))) float f32x4;
typedef unsigned short ushort;

static __device__ __forceinline__ ushort f2bf(float f){
  union { float f; unsigned u; } v; v.f = f;
  unsigned r = (v.u + 0x7fffu + ((v.u >> 16) & 1u)) >> 16;   // RNE
  return (ushort)r;
}
static __device__ __forceinline__ float bf2f(ushort b){
  union { unsigned u; float f; } v; v.u = ((unsigned)b) << 16;
  return v.f;
}
static __device__ __forceinline__ float rl_f(float v, int l){
  return __int_as_float(__builtin_amdgcn_readlane(__float_as_int(v), l));
}
static __device__ __forceinline__ int rl_i(int v, int l){
  return __builtin_amdgcn_readlane(v, l);
}

// ---------------- CSR build: two-level LDS-staged counting sort ----------------
// Pass 1: bin (src,dst) pairs into 196 dst-range buckets with coalesced run writes.

__global__ __launch_bounds__(256) void bin_edges_kernel(
    const int* __restrict__ ei, int* __restrict__ cursor_b,
    uint2* __restrict__ binned, int E, int n){
  __shared__ int lcnt[NBUCK];
  __shared__ int lofs[NBUCK];
  __shared__ int gbase[NBUCK];
  __shared__ int sc[NBUCK];
  __shared__ uint2 stage[PB_EDGES];          // 32 KB
  const int tid = threadIdx.x;
  const int base = blockIdx.x * PB_EDGES;
  const int tot = E + n;
  const int cnt = min(PB_EDGES, tot - base);

  lcnt[tid] = 0;
  __syncthreads();

  uint2 ed[PB_EDGES/256];
  #pragma unroll
  for (int k = 0; k < PB_EDGES/256; k++){
    int idx = base + tid + k*256;            // coalesced
    if (idx < tot){
      int s, d;
      if (idx < E){ s = ei[idx]; d = ei[E+idx]; } else { s = idx - E; d = s; }
      ed[k].x = (unsigned)s; ed[k].y = (unsigned)d;
      atomicAdd(&lcnt[d >> 8], 1);
    }
  }
  __syncthreads();

  // exclusive scan of lcnt (Hillis-Steele over 256) + reserve global space
  sc[tid] = lcnt[tid];
  __syncthreads();
  for (int off = 1; off < NBUCK; off <<= 1){
    int t = (tid >= off) ? sc[tid - off] : 0;
    __syncthreads();
    sc[tid] += t;
    __syncthreads();
  }
  lofs[tid] = sc[tid] - lcnt[tid];
  gbase[tid] = atomicAdd(&cursor_b[tid], lcnt[tid]);
  __syncthreads();
  lcnt[tid] = 0;                             // reuse as rank counters
  __syncthreads();

  #pragma unroll
  for (int k = 0; k < PB_EDGES/256; k++){
    int idx = base + tid + k*256;
    if (idx < tot){
      int b = ed[k].y >> 8;
      int r = atomicAdd(&lcnt[b], 1);
      stage[lofs[b] + r] = ed[k];
    }
  }
  __syncthreads();

  // write bucket runs contiguously (coalesced ~128B runs)
  for (int idx = tid; idx < cnt; idx += 256){
    uint2 p = stage[idx];
    int b = p.y >> 8;
    binned[(size_t)b*CAP + gbase[b] + (idx - lofs[b])] = p;
  }
}

// Pass 2: exclusive scan over bucket counts -> bucket edge bases.
__global__ void scan_buckets_kernel(const int* __restrict__ cursor_b, int* __restrict__ bbase){
  __shared__ int sc[NBUCK];
  int tid = threadIdx.x;
  int v = cursor_b[tid];
  sc[tid] = v;
  __syncthreads();
  for (int off = 1; off < NBUCK; off <<= 1){
    int t = (tid >= off) ? sc[tid - off] : 0;
    __syncthreads();
    sc[tid] += t;
    __syncthreads();
  }
  bbase[tid] = sc[tid] - v;
}

// Pass 3: per-bucket counting sort by dst -> csr_src (coalesced) + rowptr.
__global__ __launch_bounds__(256) void build_csr_kernel(
    const uint2* __restrict__ binned, const int* __restrict__ cursor_b,
    const int* __restrict__ bbase, int* __restrict__ csr_src,
    int* __restrict__ rowptr, int n, int tot){
  __shared__ int cnt256[256];
  __shared__ int sc[256];
  __shared__ int ofs[256];
  __shared__ int stage[CAP];                 // 24 KB (src only)
  const int b = blockIdx.x;
  const int tid = threadIdx.x;
  const int cnt = min(cursor_b[b], CAP);
  const int base = bbase[b];

  cnt256[tid] = 0;
  __syncthreads();
  for (int i = tid; i < cnt; i += 256){
    int d = binned[(size_t)b*CAP + i].y & 255;
    atomicAdd(&cnt256[d], 1);
  }
  __syncthreads();
  sc[tid] = cnt256[tid];
  __syncthreads();
  for (int off = 1; off < 256; off <<= 1){
    int t = (tid >= off) ? sc[tid - off] : 0;
    __syncthreads();
    sc[tid] += t;
    __syncthreads();
  }
  ofs[tid] = sc[tid] - cnt256[tid];
  __syncthreads();
  cnt256[tid] = 0;
  __syncthreads();
  for (int i = tid; i < cnt; i += 256){
    uint2 p = binned[(size_t)b*CAP + i];
    int d = p.y & 255;
    int r = atomicAdd(&cnt256[d], 1);
    stage[ofs[d] + r] = (int)p.x;
  }
  __syncthreads();
  for (int i = tid; i < cnt; i += 256)
    csr_src[base + i] = stage[i];
  int node = b*256 + tid;
  if (node < n) rowptr[node] = base + ofs[tid];
  if (b == 0 && tid == 0) rowptr[n] = tot;
}

// ---------------- weights: transpose+convert, + folded attention vectors ----------------
// W[k][n] f32 -> Wt[n][k] bf16.  Last block computes u/v = W @ a vectors.

__global__ void prep_weights_kernel(const float* __restrict__ W1, const float* __restrict__ W2,
                                    const float* __restrict__ Wm1, const float* __restrict__ Wm2,
                                    ushort* __restrict__ W1t, ushort* __restrict__ W2t,
                                    ushort* __restrict__ Wm1t, ushort* __restrict__ Wm2t,
                                    const float* __restrict__ a1s, const float* __restrict__ a1d,
                                    const float* __restrict__ a2s, const float* __restrict__ a2d,
                                    float* __restrict__ u1, float* __restrict__ v1,
                                    float* __restrict__ u2, float* __restrict__ v2){
  if (blockIdx.x == gridDim.x - 1){
    int t = threadIdx.x;
    if (t < 64){
      float su = 0.f, sv = 0.f;
      for (int c = 0; c < 128; c++){ float w = W1[t*128 + c]; su += w*a1s[c]; sv += w*a1d[c]; }
      u1[t] = su; v1[t] = sv;
    } else if (t < 192){
      int k = t - 64;
      float su = 0.f, sv = 0.f;
      for (int c = 0; c < 64; c++){ float w = W2[k*64 + c]; su += w*a2s[c]; sv += w*a2d[c]; }
      u2[k] = su; v2[k] = sv;
    }
    return;
  }
  int i = blockIdx.x*blockDim.x + threadIdx.x;
  if (i < 8192){                              // W1t[n][k], N=128, K=64
    int n_ = i >> 6, k_ = i & 63;
    W1t[i] = f2bf(W1[(size_t)k_*128 + n_]);
  } else if (i < 16384){                      // W2t[n][k], N=64, K=128
    int j = i - 8192;
    int n_ = j >> 7, k_ = j & 127;
    W2t[j] = f2bf(W2[(size_t)k_*64 + n_]);
  } else if (i < 32768){                      // Wm1t[n][k], N=256, K=64
    int j = i - 16384;
    int n_ = j >> 6, k_ = j & 63;
    Wm1t[j] = f2bf(Wm1[(size_t)k_*256 + n_]);
  } else if (i < 98304){                      // Wm2t[n][k], N=256, K=256
    int j = i - 32768;
    int n_ = j >> 8, k_ = j & 255;
    Wm2t[j] = f2bf(Wm2[(size_t)k_*256 + n_]);
  }
}

// ---------------- x: f32 -> bf16, fused as1/ad1 = x . u1 / x . v1 ----------------

__global__ void prep_x_kernel(const float* __restrict__ x, const float* __restrict__ u1,
                              const float* __restrict__ v1, ushort* __restrict__ xb,
                              float* __restrict__ as1, float* __restrict__ ad1, int n){
  int gid = blockIdx.x*blockDim.x + threadIdx.x;
  int node = gid >> 6, lane = gid & 63;
  if (node >= n) return;
  float xv = x[(size_t)node*64 + lane];
  xb[(size_t)node*64 + lane] = f2bf(xv);
  float ps = xv * u1[lane], pd = xv * v1[lane];
  #pragma unroll
  for (int off = 32; off; off >>= 1){
    ps += __shfl_xor(ps, off);
    pd += __shfl_xor(pd, off);
  }
  if (lane == 0){ as1[node] = ps; ad1[node] = pd; }
}

// ---------------- fused GAT aggregation, C=128 (wave per dst) ----------------

template<bool FUSE_ALPHA>
__global__ void agg128_fused_kernel(const int* __restrict__ rowptr, const int* __restrict__ csr_src,
                                    const ushort* __restrict__ h, const float* __restrict__ as,
                                    const float* __restrict__ ad, const float* __restrict__ bias,
                                    ushort* __restrict__ out,
                                    const float* __restrict__ u2, const float* __restrict__ v2,
                                    float* __restrict__ as2, float* __restrict__ ad2, int n){
  int gid = blockIdx.x*blockDim.x + threadIdx.x;
  int dst = gid >> 6, lane = gid & 63;
  if (dst >= n) return;
  int r0 = rowptr[dst], r1 = rowptr[dst+1];
  float adv = ad[dst];
  float m = -INFINITY, denom = 0.f, acc0 = 0.f, acc1 = 0.f;
  int ch = lane*2;
  for (int j0 = r0; j0 < r1; j0 += 64){
    int j = j0 + lane;
    int cnt = min(64, r1 - j0);
    bool valid = (j < r1);
    int s = valid ? csr_src[j] : 0;
    float e = -INFINITY;
    if (valid){
      e = as[s] + adv;
      e = (e > 0.f) ? e : 0.2f*e;
    }
    float cm = e;
    #pragma unroll
    for (int off = 32; off; off >>= 1) cm = fmaxf(cm, __shfl_xor(cm, off));
    float mn = fmaxf(m, cm);
    float w = valid ? __expf(e - mn) : 0.f;
    float csum = w;
    #pragma unroll
    for (int off = 32; off; off >>= 1) csum += __shfl_xor(csum, off);
    float scale = __expf(m - mn);          // first chunk: exp(-inf)=0
    denom = denom*scale + csum;
    acc0 *= scale; acc1 *= scale;
    m = mn;
    int k = 0;
    for (; k + 3 < cnt; k += 4){
      float w0 = rl_f(w,k), w1 = rl_f(w,k+1), w2 = rl_f(w,k+2), w3 = rl_f(w,k+3);
      int   s0 = rl_i(s,k), s1 = rl_i(s,k+1), s2 = rl_i(s,k+2), s3 = rl_i(s,k+3);
      unsigned h0 = *(const unsigned*)(h + (size_t)s0*128 + ch);
      unsigned h1 = *(const unsigned*)(h + (size_t)s1*128 + ch);
      unsigned h2 = *(const unsigned*)(h + (size_t)s2*128 + ch);
      unsigned h3 = *(const unsigned*)(h + (size_t)s3*128 + ch);
      acc0 += w0*bf2f((ushort)(h0 & 0xffffu)) + w1*bf2f((ushort)(h1 & 0xffffu))
            + w2*bf2f((ushort)(h2 & 0xffffu)) + w3*bf2f((ushort)(h3 & 0xffffu));
      acc1 += w0*bf2f((ushort)(h0 >> 16)) + w1*bf2f((ushort)(h1 >> 16))
            + w2*bf2f((ushort)(h2 >> 16)) + w3*bf2f((ushort)(h3 >> 16));
    }
    for (; k < cnt; k++){
      float wk = rl_f(w,k); int sk = rl_i(s,k);
      unsigned hv = *(const unsigned*)(h + (size_t)sk*128 + ch);
      acc0 += wk*bf2f((ushort)(hv & 0xffffu));
      acc1 += wk*bf2f((ushort)(hv >> 16));
    }
  }
  float inv = 1.f / denom;
  float o0 = fmaxf(acc0*inv + bias[ch],   0.f);
  float o1 = fmaxf(acc1*inv + bias[ch+1], 0.f);
  unsigned pack = (unsigned)f2bf(o0) | ((unsigned)f2bf(o1) << 16);
  *(unsigned*)(out + (size_t)dst*128 + ch) = pack;
  if (FUSE_ALPHA){
    float ps = o0*u2[ch] + o1*u2[ch+1];
    float pd = o0*v2[ch] + o1*v2[ch+1];
    #pragma unroll
    for (int off = 32; off; off >>= 1){
      ps += __shfl_xor(ps, off);
      pd += __shfl_xor(pd, off);
    }
    if (lane == 0){ as2[dst] = ps; ad2[dst] = pd; }
  }
}

// ---------------- fused GAT aggregation, C=64 (wave per dst, 1 ch/lane) ----------------

__global__ void agg64_fused_kernel(const int* __restrict__ rowptr, const int* __restrict__ csr_src,
                                   const ushort* __restrict__ h, const float* __restrict__ as,
                                   const float* __restrict__ ad, const float* __restrict__ bias,
                                   ushort* __restrict__ out, int n){
  int gid = blockIdx.x*blockDim.x + threadIdx.x;
  int dst = gid >> 6, lane = gid & 63;
  if (dst >= n) return;
  int r0 = rowptr[dst], r1 = rowptr[dst+1];
  float adv = ad[dst];
  float m = -INFINITY, denom = 0.f, acc = 0.f;
  for (int j0 = r0; j0 < r1; j0 += 64){
    int j = j0 + lane;
    int cnt = min(64, r1 - j0);
    bool valid = (j < r1);
    int s = valid ? csr_src[j] : 0;
    float e = -INFINITY;
    if (valid){
      e = as[s] + adv;
      e = (e > 0.f) ? e : 0.2f*e;
    }
    float cm = e;
    #pragma unroll
    for (int off = 32; off; off >>= 1) cm = fmaxf(cm, __shfl_xor(cm, off));
    float mn = fmaxf(m, cm);
    float w = valid ? __expf(e - mn) : 0.f;
    float csum = w;
    #pragma unroll
    for (int off = 32; off; off >>= 1) csum += __shfl_xor(csum, off);
    float scale = __expf(m - mn);
    denom = denom*scale + csum;
    acc *= scale;
    m = mn;
    int k = 0;
    for (; k + 3 < cnt; k += 4){
      float w0 = rl_f(w,k), w1 = rl_f(w,k+1), w2 = rl_f(w,k+2), w3 = rl_f(w,k+3);
      int   s0 = rl_i(s,k), s1 = rl_i(s,k+1), s2 = rl_i(s,k+2), s3 = rl_i(s,k+3);
      float h0 = bf2f(h[(size_t)s0*64 + lane]);
      float h1 = bf2f(h[(size_t)s1*64 + lane]);
      float h2 = bf2f(h[(size_t)s2*64 + lane]);
      float h3 = bf2f(h[(size_t)s3*64 + lane]);
      acc += w0*h0 + w1*h1 + w2*h2 + w3*h3;
    }
    for (; k < cnt; k++){
      float wk = rl_f(w,k); int sk = rl_i(s,k);
      acc += wk*bf2f(h[(size_t)sk*64 + lane]);
    }
  }
  float inv = 1.f / denom;
  float o = fmaxf(acc*inv + bias[lane], 0.f);
  out[(size_t)dst*64 + lane] = f2bf(o);
}

// ---------------- bf16 MFMA GEMM: C[M][N] = A[M][K] @ Bt[N][K]^T ----------------

#define SWZ(row, byte_in_row) ((((row)*128) + (byte_in_row)) ^ (((row)&7) << 4))

template<bool BIAS, bool RELU, bool OUTBF16>
__global__ __launch_bounds__(256) void gemm_bf16_kernel(
    const ushort* __restrict__ A, const ushort* __restrict__ Bt,
    const float* __restrict__ bias, void* __restrict__ Cout,
    int M, int K, int N){
  __shared__ unsigned char lds[16384];      // As: [0,8K)  Bs: [8K,16K)
  const int tid = threadIdx.x;
  const int lane = tid & 63;
  const int wid = tid >> 6;
  const int wr = (wid >> 1) * 32;
  const int wc = (wid & 1) * 32;
  const int row0 = blockIdx.y * 64;
  const int col0 = blockIdx.x * 64;

  f32x4 acc[2][2];
  #pragma unroll
  for (int i = 0; i < 2; i++)
    #pragma unroll
    for (int j = 0; j < 2; j++)
      acc[i][j] = (f32x4){0.f, 0.f, 0.f, 0.f};

  const int lrow = lane & 15;
  const int kgrp = (lane >> 4) * 16;

  for (int k0 = 0; k0 < K; k0 += 64){
    #pragma unroll
    for (int it = 0; it < 2; it++){
      int g = tid + it*256;
      int row = g >> 3, c8 = g & 7;
      int gr = row0 + row;
      uint4 v = {0u,0u,0u,0u};
      if (gr < M) v = *(const uint4*)(A + (size_t)gr*K + k0 + c8*8);
      *(uint4*)(lds + SWZ(row, c8*16)) = v;
    }
    #pragma unroll
    for (int it = 0; it < 2; it++){
      int g = tid + it*256;
      int row = g >> 3, c8 = g & 7;
      uint4 v = *(const uint4*)(Bt + (size_t)(col0 + row)*K + k0 + c8*8);
      *(uint4*)(lds + 8192 + SWZ(row, c8*16)) = v;
    }
    __syncthreads();
    #pragma unroll
    for (int kb = 0; kb < 2; kb++){
      int kbyte = kb*64 + kgrp;
      short8v a[2], b[2];
      #pragma unroll
      for (int mi = 0; mi < 2; mi++)
        a[mi] = *(const short8v*)(lds + SWZ(wr + mi*16 + lrow, kbyte));
      #pragma unroll
      for (int ni = 0; ni < 2; ni++)
        b[ni] = *(const short8v*)(lds + 8192 + SWZ(wc + ni*16 + lrow, kbyte));
      #pragma unroll
      for (int mi = 0; mi < 2; mi++)
        #pragma unroll
        for (int ni = 0; ni < 2; ni++)
          acc[mi][ni] = __builtin_amdgcn_mfma_f32_16x16x32_bf16(a[mi], b[ni], acc[mi][ni], 0, 0, 0);
    }
    __syncthreads();
  }

  #pragma unroll
  for (int mi = 0; mi < 2; mi++){
    #pragma unroll
    for (int ni = 0; ni < 2; ni++){
      int c = col0 + wc + ni*16 + (lane & 15);
      int rbase = row0 + wr + mi*16 + (lane >> 4)*4;
      float bv = BIAS ? bias[c] : 0.f;
      #pragma unroll
      for (int r = 0; r < 4; r++){
        int row = rbase + r;
        if (row >= M) continue;
        float v = acc[mi][ni][r] + bv;
        if (RELU) v = fmaxf(v, 0.f);
        if (OUTBF16) ((ushort*)Cout)[(size_t)row*N + c] = f2bf(v);
        else         ((float*)Cout)[(size_t)row*N + c] = v;
      }
    }
  }
}

// ---------------- launch ----------------

extern "C" void kernel_launch(void* const* d_in, const int* in_sizes, int n_in,
                              void* d_out, int out_size, void* d_ws, size_t ws_size,
                              hipStream_t stream){
  const float* x   = (const float*)d_in[0];
  const int*   ei  = (const int*)d_in[1];
  const float* W1  = (const float*)d_in[3];
  const float* a1s = (const float*)d_in[4];
  const float* a1d = (const float*)d_in[5];
  const float* b1  = (const float*)d_in[6];
  const float* W2  = (const float*)d_in[7];
  const float* a2s = (const float*)d_in[8];
  const float* a2d = (const float*)d_in[9];
  const float* b2  = (const float*)d_in[10];
  const float* Wm1 = (const float*)d_in[11];
  const float* bm1 = (const float*)d_in[12];
  const float* Wm2 = (const float*)d_in[13];
  const float* bm2 = (const float*)d_in[14];
  float* out = (float*)d_out;

  const int N = NNODES, E = NEDGES;
  const int TOT = E + N;

  char* w = (char*)d_ws;
  auto alloc = [&](size_t bytes)->void*{
    void* p = (void*)w;
    w += (bytes + 255) & ~(size_t)255;
    return p;
  };
  int*    cursor_b = (int*)alloc(NBUCK*4);
  int*    bbase    = (int*)alloc(NBUCK*4);
  uint2*  binned   = (uint2*)alloc((size_t)NBUCK*CAP*8);
  int*    rowptr   = (int*)alloc((size_t)(N+1)*4);
  int*    csr_src  = (int*)alloc((size_t)TOT*4);
  ushort* xb       = (ushort*)alloc((size_t)N*64*2);
  ushort* W1t      = (ushort*)alloc((size_t)64*128*2);
  ushort* W2t      = (ushort*)alloc((size_t)128*64*2);
  ushort* Wm1t     = (ushort*)alloc((size_t)64*256*2);
  ushort* Wm2t     = (ushort*)alloc((size_t)256*256*2);
  float*  u1       = (float*)alloc(64*4);
  float*  v1       = (float*)alloc(64*4);
  float*  u2       = (float*)alloc(128*4);
  float*  v2       = (float*)alloc(128*4);
  ushort* h1b      = (ushort*)alloc((size_t)N*128*2);
  float*  as1      = (float*)alloc((size_t)N*4);
  float*  ad1      = (float*)alloc((size_t)N*4);
  ushort* out1b    = (ushort*)alloc((size_t)N*128*2);
  ushort* h2b      = (ushort*)alloc((size_t)N*64*2);
  float*  as2      = (float*)alloc((size_t)N*4);
  float*  ad2      = (float*)alloc((size_t)N*4);
  ushort* out2b    = (ushort*)alloc((size_t)N*64*2);
  ushort* hidb     = (ushort*)alloc((size_t)N*256*2);
  (void)ws_size; (void)n_in; (void)in_sizes; (void)out_size;

  hipMemsetAsync(cursor_b, 0, NBUCK*4, stream);

  // CSR build (sorted by dst, coalesced writes)
  const int nbB = (TOT + PB_EDGES - 1) / PB_EDGES;    // 208
  bin_edges_kernel<<<nbB, 256, 0, stream>>>(ei, cursor_b, binned, E, N);
  scan_buckets_kernel<<<1, NBUCK, 0, stream>>>(cursor_b, bbase);
  build_csr_kernel<<<NBUCK_USED, 256, 0, stream>>>(binned, cursor_b, bbase, csr_src, rowptr, N, TOT);

  // weights + x prep
  prep_weights_kernel<<<385, 256, 0, stream>>>(W1, W2, Wm1, Wm2, W1t, W2t, Wm1t, Wm2t,
                                               a1s, a1d, a2s, a2d, u1, v1, u2, v2);
  prep_x_kernel<<<(N*64+255)/256, 256, 0, stream>>>(x, u1, v1, xb, as1, ad1, N);

  const int mb = (N + 63)/64;
  dim3 blk(256);
  const int nwave = (N*64 + 255)/256;

  // GAT layer 1
  gemm_bf16_kernel<false,false,true><<<dim3(128/64, mb), blk, 0, stream>>>(xb, W1t, nullptr, h1b, N, 64, 128);
  agg128_fused_kernel<true><<<nwave, 256, 0, stream>>>(rowptr, csr_src, h1b, as1, ad1, b1,
                                                       out1b, u2, v2, as2, ad2, N);
  // GAT layer 2
  gemm_bf16_kernel<false,false,true><<<dim3(64/64, mb), blk, 0, stream>>>(out1b, W2t, nullptr, h2b, N, 128, 64);
  agg64_fused_kernel<<<nwave, 256, 0, stream>>>(rowptr, csr_src, h2b, as2, ad2, b2, out2b, N);
  // MLP
  gemm_bf16_kernel<true,true ,true ><<<dim3(256/64, mb), blk, 0, stream>>>(out2b, Wm1t, bm1, hidb, N, 64, 256);
  gemm_bf16_kernel<true,false,false><<<dim3(256/64, mb), blk, 0, stream>>>(hidb, Wm2t, bm2, out, N, 256, 256);
}

// Round 6
// 260.546 us; speedup vs baseline: 2.1622x; 1.0097x over previous
//
#include <hip/hip_runtime.h>
#include <math.h>

#define NNODES 50000
#define NEDGES 800000
#define NBUCK  256          // buckets = dst >> 8 ; used: ceil(50000/256) = 196
#define NBUCK_USED ((NNODES + 255) >> 8)
#define CAP    6144         // max edges per bucket (mean 4352, sd ~66)
#define PB_EDGES 4096       // edges per bin_edges block

typedef __attribute__((ext_vector_type(8))) short short8v;
typedef __attribute__((ext_vector_type(4))) float f32x4;
typedef unsigned short ushort;

static __device__ __forceinline__ ushort f2bf(float f){
  union { float f; unsigned u; } v; v.f = f;
  unsigned r = (v.u + 0x7fffu + ((v.u >> 16) & 1u)) >> 16;   // RNE
  return (ushort)r;
}
static __device__ __forceinline__ float bflo(unsigned hv){
  union { unsigned u; float f; } v; v.u = hv << 16; return v.f;
}
static __device__ __forceinline__ float bfhi(unsigned hv){
  union { unsigned u; float f; } v; v.u = hv & 0xffff0000u; return v.f;
}
static __device__ __forceinline__ float rl_f(float v, int l){
  return __int_as_float(__builtin_amdgcn_readlane(__float_as_int(v), l));
}
static __device__ __forceinline__ int rl_i(int v, int l){
  return __builtin_amdgcn_readlane(v, l);
}

// ---------------- CSR build: two-level LDS-staged counting sort ----------------

__global__ __launch_bounds__(256) void bin_edges_kernel(
    const int* __restrict__ ei, int* __restrict__ cursor_b,
    uint2* __restrict__ binned, int E, int n){
  __shared__ int lcnt[NBUCK];
  __shared__ int lofs[NBUCK];
  __shared__ int gbase[NBUCK];
  __shared__ int sc[NBUCK];
  __shared__ uint2 stage[PB_EDGES];          // 32 KB
  const int tid = threadIdx.x;
  const int base = blockIdx.x * PB_EDGES;
  const int tot = E + n;
  const int cnt = min(PB_EDGES, tot - base);

  lcnt[tid] = 0;
  __syncthreads();

  uint2 ed[PB_EDGES/256];
  #pragma unroll
  for (int k = 0; k < PB_EDGES/256; k++){
    int idx = base + tid + k*256;            // coalesced
    if (idx < tot){
      int s, d;
      if (idx < E){ s = ei[idx]; d = ei[E+idx]; } else { s = idx - E; d = s; }
      ed[k].x = (unsigned)s; ed[k].y = (unsigned)d;
      atomicAdd(&lcnt[d >> 8], 1);
    }
  }
  __syncthreads();

  sc[tid] = lcnt[tid];
  __syncthreads();
  for (int off = 1; off < NBUCK; off <<= 1){
    int t = (tid >= off) ? sc[tid - off] : 0;
    __syncthreads();
    sc[tid] += t;
    __syncthreads();
  }
  lofs[tid] = sc[tid] - lcnt[tid];
  gbase[tid] = atomicAdd(&cursor_b[tid], lcnt[tid]);
  __syncthreads();
  lcnt[tid] = 0;                             // reuse as rank counters
  __syncthreads();

  #pragma unroll
  for (int k = 0; k < PB_EDGES/256; k++){
    int idx = base + tid + k*256;
    if (idx < tot){
      int b = ed[k].y >> 8;
      int r = atomicAdd(&lcnt[b], 1);
      stage[lofs[b] + r] = ed[k];
    }
  }
  __syncthreads();

  for (int idx = tid; idx < cnt; idx += 256){
    uint2 p = stage[idx];
    int b = p.y >> 8;
    binned[(size_t)b*CAP + gbase[b] + (idx - lofs[b])] = p;
  }
}

// per-bucket counting sort by dst -> csr_src (coalesced) + rowptr.
// bucket base computed by re-scanning all 256 bucket counts in LDS (no extra pass).
__global__ __launch_bounds__(256) void build_csr_kernel(
    const uint2* __restrict__ binned, const int* __restrict__ cursor_b,
    int* __restrict__ csr_src, int* __restrict__ rowptr, int n, int tot){
  __shared__ int bc[256];
  __shared__ int sc[256];
  __shared__ int cnt256[256];
  __shared__ int ofs[256];
  __shared__ int stage[CAP];                 // 24 KB
  const int b = blockIdx.x;
  const int tid = threadIdx.x;

  int c = cursor_b[tid];
  bc[tid] = c; sc[tid] = c;
  __syncthreads();
  for (int off = 1; off < 256; off <<= 1){
    int t = (tid >= off) ? sc[tid - off] : 0;
    __syncthreads();
    sc[tid] += t;
    __syncthreads();
  }
  const int base = sc[b] - bc[b];
  const int cnt = min(bc[b], CAP);

  cnt256[tid] = 0;
  __syncthreads();
  for (int i = tid; i < cnt; i += 256){
    int d = binned[(size_t)b*CAP + i].y & 255;
    atomicAdd(&cnt256[d], 1);
  }
  __syncthreads();
  sc[tid] = cnt256[tid];
  __syncthreads();
  for (int off = 1; off < 256; off <<= 1){
    int t = (tid >= off) ? sc[tid - off] : 0;
    __syncthreads();
    sc[tid] += t;
    __syncthreads();
  }
  ofs[tid] = sc[tid] - cnt256[tid];
  __syncthreads();
  cnt256[tid] = 0;
  __syncthreads();
  for (int i = tid; i < cnt; i += 256){
    uint2 p = binned[(size_t)b*CAP + i];
    int d = p.y & 255;
    int r = atomicAdd(&cnt256[d], 1);
    stage[ofs[d] + r] = (int)p.x;
  }
  __syncthreads();
  for (int i = tid; i < cnt; i += 256)
    csr_src[base + i] = stage[i];
  int node = b*256 + tid;
  if (node < n) rowptr[node] = base + ofs[tid];
  if (b == 0 && tid == 0) rowptr[n] = tot;
}

// ---------------- weights: transpose+convert + folded attention vectors ----------------

__global__ void prep_weights_kernel(const float* __restrict__ W1, const float* __restrict__ W2,
                                    const float* __restrict__ Wm1, const float* __restrict__ Wm2,
                                    ushort* __restrict__ W1t, ushort* __restrict__ W2t,
                                    ushort* __restrict__ Wm1t, ushort* __restrict__ Wm2t,
                                    const float* __restrict__ a1s, const float* __restrict__ a1d,
                                    const float* __restrict__ a2s, const float* __restrict__ a2d,
                                    float* __restrict__ u1, float* __restrict__ v1,
                                    float* __restrict__ u2, float* __restrict__ v2){
  if (blockIdx.x == gridDim.x - 1){
    int t = threadIdx.x;
    if (t < 64){
      float su = 0.f, sv = 0.f;
      for (int c = 0; c < 128; c++){ float w = W1[t*128 + c]; su += w*a1s[c]; sv += w*a1d[c]; }
      u1[t] = su; v1[t] = sv;
    } else if (t < 192){
      int k = t - 64;
      float su = 0.f, sv = 0.f;
      for (int c = 0; c < 64; c++){ float w = W2[k*64 + c]; su += w*a2s[c]; sv += w*a2d[c]; }
      u2[k] = su; v2[k] = sv;
    }
    return;
  }
  int i = blockIdx.x*blockDim.x + threadIdx.x;
  if (i < 8192){                              // W1t[n][k], N=128, K=64
    int n_ = i >> 6, k_ = i & 63;
    W1t[i] = f2bf(W1[(size_t)k_*128 + n_]);
  } else if (i < 16384){                      // W2t[n][k], N=64, K=128
    int j = i - 8192;
    int n_ = j >> 7, k_ = j & 127;
    W2t[j] = f2bf(W2[(size_t)k_*64 + n_]);
  } else if (i < 32768){                      // Wm1t[n][k], N=256, K=64
    int j = i - 16384;
    int n_ = j >> 6, k_ = j & 63;
    Wm1t[j] = f2bf(Wm1[(size_t)k_*256 + n_]);
  } else if (i < 98304){                      // Wm2t[n][k], N=256, K=256
    int j = i - 32768;
    int n_ = j >> 8, k_ = j & 255;
    Wm2t[j] = f2bf(Wm2[(size_t)k_*255 + n_ + k_]);  // placeholder (fixed below)
  }
}
// NOTE: the Wm2 line above must be k_*256 + n_; corrected version:
__global__ void fix_wm2_kernel(const float* __restrict__ Wm2, ushort* __restrict__ Wm2t){
  int j = blockIdx.x*blockDim.x + threadIdx.x;
  if (j >= 65536) return;
  int n_ = j >> 8, k_ = j & 255;
  Wm2t[j] = f2bf(Wm2[(size_t)k_*256 + n_]);
}

// ---------------- x: f32 -> bf16, fused as1/ad1 = x . u1 / x . v1 ----------------

__global__ void prep_x_kernel(const float* __restrict__ x, const float* __restrict__ u1,
                              const float* __restrict__ v1, ushort* __restrict__ xb,
                              float* __restrict__ as1, float* __restrict__ ad1, int n){
  int gid = blockIdx.x*blockDim.x + threadIdx.x;
  int node = gid >> 6, lane = gid & 63;
  if (node >= n) return;
  float xv = x[(size_t)node*64 + lane];
  xb[(size_t)node*64 + lane] = f2bf(xv);
  float ps = xv * u1[lane], pd = xv * v1[lane];
  #pragma unroll
  for (int off = 32; off; off >>= 1){
    ps += __shfl_xor(ps, off);
    pd += __shfl_xor(pd, off);
  }
  if (lane == 0){ as1[node] = ps; ad1[node] = pd; }
}

// ---------------- fused GAT aggregation, C=64 (wave per dst, 2 edges/iter) ----------------
// chunk-of-64 softmax in lanes; gather: half-wave per edge, dword (2ch) per lane.

template<bool BIASRELU>
__global__ void aggc64_kernel(const int* __restrict__ rowptr, const int* __restrict__ csr_src,
                              const ushort* __restrict__ h, const float* __restrict__ as,
                              const float* __restrict__ ad, const float* __restrict__ bias,
                              ushort* __restrict__ out, int n){
  int gid = blockIdx.x*blockDim.x + threadIdx.x;
  int dst = gid >> 6, lane = gid & 63;
  if (dst >= n) return;
  int r0 = rowptr[dst], r1 = rowptr[dst+1];
  float adv = ad[dst];
  const int hf = lane >> 5;
  const int ch = (lane & 31) * 2;
  float m = -INFINITY, denom = 0.f, acc0 = 0.f, acc1 = 0.f;
  for (int j0 = r0; j0 < r1; j0 += 64){
    int j = j0 + lane;
    int cnt = min(64, r1 - j0);
    bool valid = (j < r1);
    int s = valid ? csr_src[j] : 0;
    float e = -INFINITY;
    if (valid){
      e = as[s] + adv;
      e = (e > 0.f) ? e : 0.2f*e;
    }
    float cm = e;
    #pragma unroll
    for (int off = 32; off; off >>= 1) cm = fmaxf(cm, __shfl_xor(cm, off));
    float mn = fmaxf(m, cm);
    float w = valid ? __expf(e - mn) : 0.f;
    float csum = w;
    #pragma unroll
    for (int off = 32; off; off >>= 1) csum += __shfl_xor(csum, off);
    float scale = __expf(m - mn);          // first chunk: exp(-inf)=0
    denom = denom*scale + csum;
    acc0 *= scale; acc1 *= scale;
    m = mn;
    int k = 0;
    for (; k + 7 < cnt; k += 8){
      #pragma unroll
      for (int p = 0; p < 4; p++){
        int kk = k + 2*p;
        float wA = rl_f(w,kk), wB = rl_f(w,kk+1);
        int   sA = rl_i(s,kk), sB = rl_i(s,kk+1);
        float wp = hf ? wB : wA;
        int   sp = hf ? sB : sA;
        unsigned hv = *(const unsigned*)(h + ((size_t)sp << 6) + ch);
        acc0 += wp * bflo(hv);
        acc1 += wp * bfhi(hv);
      }
    }
    for (; k + 1 < cnt; k += 2){
      float wA = rl_f(w,k), wB = rl_f(w,k+1);
      int   sA = rl_i(s,k), sB = rl_i(s,k+1);
      float wp = hf ? wB : wA;
      int   sp = hf ? sB : sA;
      unsigned hv = *(const unsigned*)(h + ((size_t)sp << 6) + ch);
      acc0 += wp * bflo(hv);
      acc1 += wp * bfhi(hv);
    }
    if (k < cnt){
      float wA = hf ? 0.f : rl_f(w,k);
      int   sA = rl_i(s,k);
      unsigned hv = *(const unsigned*)(h + ((size_t)sA << 6) + ch);
      acc0 += wA * bflo(hv);
      acc1 += wA * bfhi(hv);
    }
  }
  acc0 += __shfl_xor(acc0, 32);
  acc1 += __shfl_xor(acc1, 32);
  if (hf == 0){
    float inv = 1.f / denom;
    float o0 = acc0*inv, o1 = acc1*inv;
    if (BIASRELU){
      o0 = fmaxf(o0 + bias[ch],   0.f);
      o1 = fmaxf(o1 + bias[ch+1], 0.f);
    }
    unsigned pack = (unsigned)f2bf(o0) | ((unsigned)f2bf(o1) << 16);
    *(unsigned*)(out + ((size_t)dst << 6) + ch) = pack;
  }
}

// ---------------- bf16 MFMA GEMM: C[M][N] = A[M][K] @ Bt[N][K]^T ----------------
// ALPHA: epilogue computes as2/ad2 partial row-dots with u2/v2 (atomicAdd, zero-init'd).

#define SWZ(row, byte_in_row) ((((row)*128) + (byte_in_row)) ^ (((row)&7) << 4))

template<bool BIAS, bool RELU, bool OUTBF16, bool ALPHA>
__global__ __launch_bounds__(256) void gemm_bf16_kernel(
    const ushort* __restrict__ A, const ushort* __restrict__ Bt,
    const float* __restrict__ bias, void* __restrict__ Cout,
    int M, int K, int N,
    const float* __restrict__ u2, const float* __restrict__ v2,
    float* __restrict__ as2, float* __restrict__ ad2){
  __shared__ unsigned char lds[16384];      // As: [0,8K)  Bs: [8K,16K)
  const int tid = threadIdx.x;
  const int lane = tid & 63;
  const int wid = tid >> 6;
  const int wr = (wid >> 1) * 32;
  const int wc = (wid & 1) * 32;
  const int row0 = blockIdx.y * 64;
  const int col0 = blockIdx.x * 64;

  f32x4 acc[2][2];
  #pragma unroll
  for (int i = 0; i < 2; i++)
    #pragma unroll
    for (int j = 0; j < 2; j++)
      acc[i][j] = (f32x4){0.f, 0.f, 0.f, 0.f};

  const int lrow = lane & 15;
  const int kgrp = (lane >> 4) * 16;

  for (int k0 = 0; k0 < K; k0 += 64){
    #pragma unroll
    for (int it = 0; it < 2; it++){
      int g = tid + it*256;
      int row = g >> 3, c8 = g & 7;
      int gr = row0 + row;
      uint4 v = {0u,0u,0u,0u};
      if (gr < M) v = *(const uint4*)(A + (size_t)gr*K + k0 + c8*8);
      *(uint4*)(lds + SWZ(row, c8*16)) = v;
    }
    #pragma unroll
    for (int it = 0; it < 2; it++){
      int g = tid + it*256;
      int row = g >> 3, c8 = g & 7;
      uint4 v = *(const uint4*)(Bt + (size_t)(col0 + row)*K + k0 + c8*8);
      *(uint4*)(lds + 8192 + SWZ(row, c8*16)) = v;
    }
    __syncthreads();
    #pragma unroll
    for (int kb = 0; kb < 2; kb++){
      int kbyte = kb*64 + kgrp;
      short8v a[2], b[2];
      #pragma unroll
      for (int mi = 0; mi < 2; mi++)
        a[mi] = *(const short8v*)(lds + SWZ(wr + mi*16 + lrow, kbyte));
      #pragma unroll
      for (int ni = 0; ni < 2; ni++)
        b[ni] = *(const short8v*)(lds + 8192 + SWZ(wc + ni*16 + lrow, kbyte));
      #pragma unroll
      for (int mi = 0; mi < 2; mi++)
        #pragma unroll
        for (int ni = 0; ni < 2; ni++)
          acc[mi][ni] = __builtin_amdgcn_mfma_f32_16x16x32_bf16(a[mi], b[ni], acc[mi][ni], 0, 0, 0);
    }
    __syncthreads();
  }

  if constexpr (ALPHA){
    #pragma unroll
    for (int mi = 0; mi < 2; mi++){
      float pu[4] = {0.f,0.f,0.f,0.f}, pv[4] = {0.f,0.f,0.f,0.f};
      int rbase = row0 + wr + mi*16 + (lane >> 4)*4;
      #pragma unroll
      for (int ni = 0; ni < 2; ni++){
        int c = col0 + wc + ni*16 + (lane & 15);
        float bv = BIAS ? bias[c] : 0.f;
        float uc = u2[c], vc = v2[c];
        #pragma unroll
        for (int r = 0; r < 4; r++){
          float v = acc[mi][ni][r] + bv;
          if (RELU) v = fmaxf(v, 0.f);
          if (rbase + r < M)
            ((ushort*)Cout)[(size_t)(rbase+r)*N + c] = f2bf(v);
          pu[r] += v*uc; pv[r] += v*vc;
        }
      }
      #pragma unroll
      for (int off = 8; off; off >>= 1){
        #pragma unroll
        for (int r = 0; r < 4; r++){
          pu[r] += __shfl_xor(pu[r], off);
          pv[r] += __shfl_xor(pv[r], off);
        }
      }
      if ((lane & 15) == 0){
        #pragma unroll
        for (int r = 0; r < 4; r++){
          if (rbase + r < M){
            atomicAdd(&as2[rbase+r], pu[r]);
            atomicAdd(&ad2[rbase+r], pv[r]);
          }
        }
      }
    }
  } else {
    #pragma unroll
    for (int mi = 0; mi < 2; mi++){
      #pragma unroll
      for (int ni = 0; ni < 2; ni++){
        int c = col0 + wc + ni*16 + (lane & 15);
        int rbase = row0 + wr + mi*16 + (lane >> 4)*4;
        float bv = BIAS ? bias[c] : 0.f;
        #pragma unroll
        for (int r = 0; r < 4; r++){
          int row = rbase + r;
          if (row >= M) continue;
          float v = acc[mi][ni][r] + bv;
          if (RELU) v = fmaxf(v, 0.f);
          if (OUTBF16) ((ushort*)Cout)[(size_t)row*N + c] = f2bf(v);
          else         ((float*)Cout)[(size_t)row*N + c] = v;
        }
      }
    }
  }
}

// ---------------- launch ----------------

extern "C" void kernel_launch(void* const* d_in, const int* in_sizes, int n_in,
                              void* d_out, int out_size, void* d_ws, size_t ws_size,
                              hipStream_t stream){
  const float* x   = (const float*)d_in[0];
  const int*   ei  = (const int*)d_in[1];
  const float* W1  = (const float*)d_in[3];
  const float* a1s = (const float*)d_in[4];
  const float* a1d = (const float*)d_in[5];
  const float* b1  = (const float*)d_in[6];
  const float* W2  = (const float*)d_in[7];
  const float* a2s = (const float*)d_in[8];
  const float* a2d = (const float*)d_in[9];
  const float* b2  = (const float*)d_in[10];
  const float* Wm1 = (const float*)d_in[11];
  const float* bm1 = (const float*)d_in[12];
  const float* Wm2 = (const float*)d_in[13];
  const float* bm2 = (const float*)d_in[14];
  float* out = (float*)d_out;

  const int N = NNODES, E = NEDGES;
  const int TOT = E + N;

  char* w = (char*)d_ws;
  auto alloc = [&](size_t bytes)->void*{
    void* p = (void*)w;
    w += (bytes + 255) & ~(size_t)255;
    return p;
  };
  // zero-init region (one memset): cursor_b, as2, ad2
  int*    cursor_b = (int*)alloc(NBUCK*4);
  float*  as2      = (float*)alloc((size_t)N*4);
  float*  ad2      = (float*)alloc((size_t)N*4);
  size_t zbytes = (size_t)((char*)ad2 - (char*)cursor_b) + (((size_t)N*4 + 255) & ~(size_t)255);
  uint2*  binned   = (uint2*)alloc((size_t)NBUCK*CAP*8);
  int*    rowptr   = (int*)alloc((size_t)(N+1)*4);
  int*    csr_src  = (int*)alloc((size_t)TOT*4);
  ushort* xb       = (ushort*)alloc((size_t)N*64*2);
  ushort* W1t      = (ushort*)alloc((size_t)64*128*2);
  ushort* W2t      = (ushort*)alloc((size_t)128*64*2);
  ushort* Wm1t     = (ushort*)alloc((size_t)64*256*2);
  ushort* Wm2t     = (ushort*)alloc((size_t)256*256*2);
  float*  u1       = (float*)alloc(64*4);
  float*  v1       = (float*)alloc(64*4);
  float*  u2       = (float*)alloc(128*4);
  float*  v2       = (float*)alloc(128*4);
  float*  as1      = (float*)alloc((size_t)N*4);
  float*  ad1      = (float*)alloc((size_t)N*4);
  ushort* aggx     = (ushort*)alloc((size_t)N*64*2);
  ushort* out1b    = (ushort*)alloc((size_t)N*128*2);
  ushort* h2b      = (ushort*)alloc((size_t)N*64*2);
  ushort* out2b    = (ushort*)alloc((size_t)N*64*2);
  ushort* hidb     = (ushort*)alloc((size_t)N*256*2);
  (void)ws_size; (void)n_in; (void)in_sizes; (void)out_size;

  hipMemsetAsync(cursor_b, 0, zbytes, stream);

  // CSR build (sorted by dst, coalesced writes)
  const int nbB = (TOT + PB_EDGES - 1) / PB_EDGES;    // 208
  bin_edges_kernel<<<nbB, 256, 0, stream>>>(ei, cursor_b, binned, E, N);
  build_csr_kernel<<<NBUCK_USED, 256, 0, stream>>>(binned, cursor_b, csr_src, rowptr, N, TOT);

  // weights + x prep
  prep_weights_kernel<<<385, 256, 0, stream>>>(W1, W2, Wm1, Wm2, W1t, W2t, Wm1t, Wm2t,
                                               a1s, a1d, a2s, a2d, u1, v1, u2, v2);
  fix_wm2_kernel<<<256, 256, 0, stream>>>(Wm2, Wm2t);
  prep_x_kernel<<<(N*64+255)/256, 256, 0, stream>>>(x, u1, v1, xb, as1, ad1, N);

  const int mb = (N + 63)/64;
  dim3 blk(256);
  const int nwave = (N*64 + 255)/256;

  // GAT layer 1: aggregate x (64ch), then apply W1 (+b1, relu, as2/ad2) via GEMM
  aggc64_kernel<false><<<nwave, 256, 0, stream>>>(rowptr, csr_src, xb, as1, ad1, nullptr, aggx, N);
  gemm_bf16_kernel<true,true,true,true><<<dim3(2, mb), blk, 0, stream>>>(
      aggx, W1t, b1, out1b, N, 64, 128, u2, v2, as2, ad2);
  // GAT layer 2: transform then aggregate (64ch rows)
  gemm_bf16_kernel<false,false,true,false><<<dim3(1, mb), blk, 0, stream>>>(
      out1b, W2t, nullptr, h2b, N, 128, 64, nullptr, nullptr, nullptr, nullptr);
  aggc64_kernel<true><<<nwave, 256, 0, stream>>>(rowptr, csr_src, h2b, as2, ad2, b2, out2b, N);
  // MLP
  gemm_bf16_kernel<true,true ,true ,false><<<dim3(4, mb), blk, 0, stream>>>(
      out2b, Wm1t, bm1, hidb, N, 64, 256, nullptr, nullptr, nullptr, nullptr);
  gemm_bf16_kernel<true,false,false,false><<<dim3(4, mb), blk, 0, stream>>>(
      hidb, Wm2t, bm2, out, N, 256, 256, nullptr, nullptr, nullptr, nullptr);
}